// Round 2
// baseline (3224.725 us; speedup 1.0000x reference)
//
#include <hip/hip_runtime.h>
#include <math.h>

// Problem constants (B=2, S=2048, H=1024, NH=8, HD=128)
static constexpr int Bz = 2;
static constexpr int Sq = 2048;
static constexpr int Hh = 1024;
static constexpr int NH = 8;
static constexpr int HD = 128;
static constexpr int H3 = 3072;
static constexpr int H6 = 6144;

// Workspace layout (floats). Total ~152.1 MB.
static constexpr size_t FUSED_OFF = 0;          // B*S*6H = 25,165,824
static constexpr size_t COMB_OFF  = 25165824;   // B*S*3H = 12,582,912
static constexpr size_t TAB_OFF   = 37748736;   // S*64 float2 = 262,144 floats
static constexpr size_t FLAG_OFF  = 38010880;   // 1 int

__device__ __forceinline__ float silu_(float x) { return x / (1.0f + expf(-x)); }
__device__ __forceinline__ float dot4_(float4 a, float4 b) {
  return a.x * b.x + a.y * b.y + a.z * b.z + a.w * b.w;
}
__device__ __forceinline__ void fma4_(float4& a, float s, float4 v) {
  a.x += s * v.x; a.y += s * v.y; a.z += s * v.z; a.w += s * v.w;
}

// ---------------- K0a: mask dtype detect. If any 32-bit word > 1, data is byte-packed bools.
__global__ __launch_bounds__(256) void hstu_mask_detect(const unsigned int* __restrict__ m,
                                                        int* __restrict__ flag) {
  __shared__ int s_any;
  if (threadIdx.x == 0) s_any = 0;
  __syncthreads();
  int any = 0;
  for (int i = threadIdx.x; i < 65536; i += 256)
    if (m[i] > 1u) any = 1;
  if (any) s_any = 1;  // benign race: all writers store 1
  __syncthreads();
  if (threadIdx.x == 0) *flag = s_any;
}

// ---------------- K0b: rope cos/sin table: tab[s*64+i] = {cos, sin}(s * 10000^(-i/64))
__global__ __launch_bounds__(256) void hstu_tab(float* __restrict__ tab) {
  int t = blockIdx.x * 256 + threadIdx.x;  // < S*64 = 131072
  int i = t & 63;
  int s = t >> 6;
  float inv = powf(10000.0f, -(float)i / 64.0f);
  float ang = (float)s * inv;
  float sn, cs;
  sincosf(ang, &sn, &cs);
  tab[2 * t + 0] = cs;
  tab[2 * t + 1] = sn;
}

// ---------------- K1: fused = silu(hidden @ W_qkvu)   M=4096 K=1024 N=6144
__global__ __launch_bounds__(256) void hstu_gemm1(const float* __restrict__ A,
                                                  const float* __restrict__ Bw,
                                                  float* __restrict__ C) {
  constexpr int K = Hh, N = H6;
  __shared__ float As[8][128];
  __shared__ float Bs[8][128];
  const int tid = threadIdx.x;
  const int row0 = blockIdx.y * 128;
  const int col0 = blockIdx.x * 128;
  const int tx = tid & 15, ty = tid >> 4;
  float acc[8][8];
#pragma unroll
  for (int i = 0; i < 8; ++i)
#pragma unroll
    for (int j = 0; j < 8; ++j) acc[i][j] = 0.f;

  const int arow = tid >> 1, acol = (tid & 1) << 2;
  const int brow = tid >> 5, bcol = (tid & 31) << 2;
  for (int k0 = 0; k0 < K; k0 += 8) {
    float4 av = *(const float4*)&A[(size_t)(row0 + arow) * K + k0 + acol];
    As[acol + 0][arow] = av.x;
    As[acol + 1][arow] = av.y;
    As[acol + 2][arow] = av.z;
    As[acol + 3][arow] = av.w;
    *(float4*)&Bs[brow][bcol] = *(const float4*)&Bw[(size_t)(k0 + brow) * N + col0 + bcol];
    __syncthreads();
#pragma unroll
    for (int kk = 0; kk < 8; ++kk) {
      float4 a0 = *(const float4*)&As[kk][ty * 8];
      float4 a1 = *(const float4*)&As[kk][ty * 8 + 4];
      float4 b0 = *(const float4*)&Bs[kk][tx * 8];
      float4 b1 = *(const float4*)&Bs[kk][tx * 8 + 4];
      float a_[8] = {a0.x, a0.y, a0.z, a0.w, a1.x, a1.y, a1.z, a1.w};
      float b_[8] = {b0.x, b0.y, b0.z, b0.w, b1.x, b1.y, b1.z, b1.w};
#pragma unroll
      for (int i = 0; i < 8; ++i)
#pragma unroll
        for (int j = 0; j < 8; ++j) acc[i][j] += a_[i] * b_[j];
    }
    __syncthreads();
  }
#pragma unroll
  for (int i = 0; i < 8; ++i) {
    const size_t crow = (size_t)(row0 + ty * 8 + i) * N + col0 + tx * 8;
#pragma unroll
    for (int jq = 0; jq < 2; ++jq) {
      float4 o;
      o.x = silu_(acc[i][jq * 4 + 0]);
      o.y = silu_(acc[i][jq * 4 + 1]);
      o.z = silu_(acc[i][jq * 4 + 2]);
      o.w = silu_(acc[i][jq * 4 + 3]);
      *(float4*)&C[crow + jq * 4] = o;
    }
  }
}

// ---------------- K2: fused attention. Per block: (b, h, 16 q-rows), loop m-tiles of 32.
// Output layout per reference: comb[b][n][h*384 + {0:rope | 128:ts | 256:plain} + d]
__global__ __launch_bounds__(256) void hstu_attn(const float* __restrict__ fused,
                                                 const float2* __restrict__ tab,
                                                 const int* __restrict__ mask32,
                                                 const unsigned char* __restrict__ mask8,
                                                 const int* __restrict__ mflag,
                                                 const float* __restrict__ bias,
                                                 float* __restrict__ comb) {
  __shared__ __align__(16) float qs[16][132];
  __shared__ __align__(16) float qrs[16][132];
  __shared__ __align__(16) float ks[32][132];   // k in phase1, v in phase2
  __shared__ __align__(16) float krs[32][132];
  __shared__ float spl[16][33];
  __shared__ float sro[16][33];
  __shared__ float sbi[16][33];

  const int tid = threadIdx.x;
  const int n0 = blockIdx.x * 16;
  const int h = blockIdx.y;
  const int b = blockIdx.z;
  const float inv_s = 1.0f / 2048.0f;
  const int m_u8 = *mflag;  // uniform

  // stage q + roped q (16 rows x 128), rope from table at position n0+row
  {
    const int row = tid >> 4;
    const int cb = (tid & 15) << 2;
    const float* qsrc = &fused[(size_t)(b * Sq + n0 + row) * H6 + 4 * Hh + h * HD];
    const float2* trow = &tab[(size_t)(n0 + row) * 64];
#pragma unroll
    for (int c = 0; c < 2; ++c) {
      const int col = cb + (c << 6);
      float4 qv = *(const float4*)&qsrc[col];
      *(float4*)&qs[row][col] = qv;
      float2 t0 = trow[col >> 1];
      float2 t1 = trow[(col >> 1) + 1];
      qrs[row][col + 0] = qv.x * t0.x - qv.y * t0.y;
      qrs[row][col + 1] = qv.y * t0.x + qv.x * t0.y;
      qrs[row][col + 2] = qv.z * t1.x - qv.w * t1.y;
      qrs[row][col + 3] = qv.w * t1.x + qv.z * t1.y;
    }
  }

  const int dc = (tid & 31) << 2;
  const int rb = tid >> 5;
  float4 accR[2], accT[2], accP[2];
#pragma unroll
  for (int ri = 0; ri < 2; ++ri) {
    accR[ri] = make_float4(0.f, 0.f, 0.f, 0.f);
    accT[ri] = make_float4(0.f, 0.f, 0.f, 0.f);
    accP[ri] = make_float4(0.f, 0.f, 0.f, 0.f);
  }

  for (int m0 = 0; m0 < Sq; m0 += 32) {
    __syncthreads();  // prev phase2 done (and q-stage visible on first iter)
    // stage k + roped k (32 rows x 128)
    {
      const int row = tid >> 3;
      const int cb = (tid & 7) << 2;
      const float* ksrc = &fused[(size_t)(b * Sq + m0 + row) * H6 + 5 * Hh + h * HD];
      const float2* trow = &tab[(size_t)(m0 + row) * 64];
#pragma unroll
      for (int c = 0; c < 4; ++c) {
        const int col = cb + (c << 5);
        float4 kv = *(const float4*)&ksrc[col];
        *(float4*)&ks[row][col] = kv;
        float2 t0 = trow[col >> 1];
        float2 t1 = trow[(col >> 1) + 1];
        krs[row][col + 0] = kv.x * t0.x - kv.y * t0.y;
        krs[row][col + 1] = kv.y * t0.x + kv.x * t0.y;
        krs[row][col + 2] = kv.z * t1.x - kv.w * t1.y;
        krs[row][col + 3] = kv.w * t1.x + kv.z * t1.y;
      }
    }
    __syncthreads();
    // phase1: scores 16x32 (each thread: 1 row x 2 m-cols x {plain,rope})
    {
      const int r = tid & 15;
      const int mA = tid >> 4;
      const int mB = mA + 16;
      float dplA = 0.f, droA = 0.f, dplB = 0.f, droB = 0.f;
#pragma unroll 4
      for (int d4 = 0; d4 < 32; ++d4) {
        const int d = d4 << 2;
        float4 qv = *(const float4*)&qs[r][d];
        float4 qrv = *(const float4*)&qrs[r][d];
        float4 ka = *(const float4*)&ks[mA][d];
        float4 kra = *(const float4*)&krs[mA][d];
        float4 kb = *(const float4*)&ks[mB][d];
        float4 krb = *(const float4*)&krs[mB][d];
        dplA += dot4_(qv, ka);
        droA += dot4_(qrv, kra);
        dplB += dot4_(qv, kb);
        droB += dot4_(qrv, krb);
      }
      const size_t ibase = (size_t)(b * Sq + n0 + r) * Sq + m0;
      const int mkA = m_u8 ? (int)mask8[ibase + mA] : mask32[ibase + mA];
      const int mkB = m_u8 ? (int)mask8[ibase + mB] : mask32[ibase + mB];
      const float bvA = bias[ibase + mA];
      const float bvB = bias[ibase + mB];
      spl[r][mA] = mkA ? fmaxf(dplA, 0.f) * inv_s : 0.f;
      sro[r][mA] = mkA ? fmaxf(droA, 0.f) * inv_s : 0.f;
      sbi[r][mA] = mkA ? bvA : 0.f;
      spl[r][mB] = mkB ? fmaxf(dplB, 0.f) * inv_s : 0.f;
      sro[r][mB] = mkB ? fmaxf(droB, 0.f) * inv_s : 0.f;
      sbi[r][mB] = mkB ? bvB : 0.f;
    }
    __syncthreads();
    // stage v into ks (k fully consumed)
    {
      const int row = tid >> 3;
      const int cb = (tid & 7) << 2;
      const float* vsrc = &fused[(size_t)(b * Sq + m0 + row) * H6 + 3 * Hh + h * HD];
#pragma unroll
      for (int c = 0; c < 4; ++c) {
        const int col = cb + (c << 5);
        *(float4*)&ks[row][col] = *(const float4*)&vsrc[col];
      }
    }
    __syncthreads();
    // phase2: acc[16][128] += scores @ v (thread: 2 rows x 4 cols x 3 types)
#pragma unroll 4
    for (int m = 0; m < 32; ++m) {
      float4 v4 = *(const float4*)&ks[m][dc];
#pragma unroll
      for (int ri = 0; ri < 2; ++ri) {
        const int r = rb + (ri << 3);
        fma4_(accP[ri], spl[r][m], v4);
        fma4_(accR[ri], sro[r][m], v4);
        fma4_(accT[ri], sbi[r][m], v4);
      }
    }
  }
  // per-head-interleaved layout: [h*384 + {0:rope,128:ts,256:plain} + d]
#pragma unroll
  for (int ri = 0; ri < 2; ++ri) {
    const int gn = n0 + rb + (ri << 3);
    const size_t base = (size_t)(b * Sq + gn) * H3 + h * (3 * HD) + dc;
    *(float4*)&comb[base] = accR[ri];               // rope_out
    *(float4*)&comb[base + HD] = accT[ri];          // ts_out
    *(float4*)&comb[base + 2 * HD] = accP[ri];      // plain_out
  }
}

// ---------------- K3: out = (comb*gated) @ W_out + b_out + hidden   M=4096 K=3072 N=1024
__global__ __launch_bounds__(256) void hstu_gemm2(const float* __restrict__ comb,
                                                  const float* __restrict__ fused,
                                                  const float* __restrict__ Bw,
                                                  const float* __restrict__ bout,
                                                  const float* __restrict__ hidden,
                                                  float* __restrict__ C) {
  constexpr int K = H3, N = Hh;
  __shared__ float As[8][128];
  __shared__ float Bs[8][128];
  const int tid = threadIdx.x;
  const int row0 = blockIdx.y * 128;
  const int col0 = blockIdx.x * 128;
  const int tx = tid & 15, ty = tid >> 4;
  float acc[8][8];
#pragma unroll
  for (int i = 0; i < 8; ++i)
#pragma unroll
    for (int j = 0; j < 8; ++j) acc[i][j] = 0.f;

  const int arow = tid >> 1, acol = (tid & 1) << 2;
  const int brow = tid >> 5, bcol = (tid & 31) << 2;
  for (int k0 = 0; k0 < K; k0 += 8) {
    const size_t am = (size_t)(row0 + arow);
    float4 c4 = *(const float4*)&comb[am * H3 + k0 + acol];
    float4 g4 = *(const float4*)&fused[am * H6 + k0 + acol];  // gated = fused[:, :3H]
    As[acol + 0][arow] = c4.x * g4.x;
    As[acol + 1][arow] = c4.y * g4.y;
    As[acol + 2][arow] = c4.z * g4.z;
    As[acol + 3][arow] = c4.w * g4.w;
    *(float4*)&Bs[brow][bcol] = *(const float4*)&Bw[(size_t)(k0 + brow) * N + col0 + bcol];
    __syncthreads();
#pragma unroll
    for (int kk = 0; kk < 8; ++kk) {
      float4 a0 = *(const float4*)&As[kk][ty * 8];
      float4 a1 = *(const float4*)&As[kk][ty * 8 + 4];
      float4 b0 = *(const float4*)&Bs[kk][tx * 8];
      float4 b1 = *(const float4*)&Bs[kk][tx * 8 + 4];
      float a_[8] = {a0.x, a0.y, a0.z, a0.w, a1.x, a1.y, a1.z, a1.w};
      float b_[8] = {b0.x, b0.y, b0.z, b0.w, b1.x, b1.y, b1.z, b1.w};
#pragma unroll
      for (int i = 0; i < 8; ++i)
#pragma unroll
        for (int j = 0; j < 8; ++j) acc[i][j] += a_[i] * b_[j];
    }
    __syncthreads();
  }
  float4 bo[2];
  bo[0] = *(const float4*)&bout[col0 + tx * 8];
  bo[1] = *(const float4*)&bout[col0 + tx * 8 + 4];
#pragma unroll
  for (int i = 0; i < 8; ++i) {
    const int gr = row0 + ty * 8 + i;
    const size_t crow = (size_t)gr * N + col0 + tx * 8;
#pragma unroll
    for (int jq = 0; jq < 2; ++jq) {
      float4 hd = *(const float4*)&hidden[crow + jq * 4];
      float4 o;
      o.x = acc[i][jq * 4 + 0] + bo[jq].x + hd.x;
      o.y = acc[i][jq * 4 + 1] + bo[jq].y + hd.y;
      o.z = acc[i][jq * 4 + 2] + bo[jq].z + hd.z;
      o.w = acc[i][jq * 4 + 3] + bo[jq].w + hd.w;
      *(float4*)&C[crow + jq * 4] = o;
    }
  }
}

// ---------------- K4: in-place RMS norm per row of d_out (4096 rows x 1024)
__global__ __launch_bounds__(256) void hstu_rms(float* __restrict__ y,
                                                const float* __restrict__ w) {
  __shared__ float red[4];
  const int row = blockIdx.x;
  const int tid = threadIdx.x;
  float4 v = *(float4*)&y[(size_t)row * Hh + tid * 4];
  float ss = v.x * v.x + v.y * v.y + v.z * v.z + v.w * v.w;
#pragma unroll
  for (int o = 32; o > 0; o >>= 1) ss += __shfl_down(ss, o);
  if ((tid & 63) == 0) red[tid >> 6] = ss;
  __syncthreads();
  const float tot = red[0] + red[1] + red[2] + red[3];
  const float r = 1.0f / sqrtf(tot / (float)Hh + 1e-6f);
  float4 wv = *(const float4*)&w[tid * 4];
  v.x *= r * wv.x;
  v.y *= r * wv.y;
  v.z *= r * wv.z;
  v.w *= r * wv.w;
  *(float4*)&y[(size_t)row * Hh + tid * 4] = v;
}

extern "C" void kernel_launch(void* const* d_in, const int* in_sizes, int n_in,
                              void* d_out, int out_size, void* d_ws, size_t ws_size,
                              hipStream_t stream) {
  const float* hidden = (const float*)d_in[0];
  const void* mask = d_in[1];                // bool mask: int32 or uint8 (detected)
  const float* bias = (const float*)d_in[2];
  const float* Wqkvu = (const float*)d_in[3];
  const float* Wout = (const float*)d_in[4];
  const float* bout = (const float*)d_in[5];
  const float* rmsw = (const float*)d_in[6];
  float* out = (float*)d_out;
  float* ws = (float*)d_ws;  // needs >= ~152.1 MB

  float* fused = ws + FUSED_OFF;
  float* comb = ws + COMB_OFF;
  float* tab = ws + TAB_OFF;
  int* mflag = (int*)(ws + FLAG_OFF);

  hstu_mask_detect<<<1, 256, 0, stream>>>((const unsigned int*)mask, mflag);
  hstu_tab<<<512, 256, 0, stream>>>(tab);
  hstu_gemm1<<<dim3(H6 / 128, (Bz * Sq) / 128), 256, 0, stream>>>(hidden, Wqkvu, fused);
  hstu_attn<<<dim3(Sq / 16, NH, Bz), 256, 0, stream>>>(
      fused, (const float2*)tab, (const int*)mask, (const unsigned char*)mask, mflag, bias, comb);
  hstu_gemm2<<<dim3(Hh / 128, (Bz * Sq) / 128), 256, 0, stream>>>(comb, fused, Wout, bout, hidden, out);
  hstu_rms<<<Bz * Sq, 256, 0, stream>>>(out, rmsw);
}

// Round 3
// 1638.732 us; speedup vs baseline: 1.9678x; 1.9678x over previous
//
#include <hip/hip_runtime.h>
#include <math.h>

// Problem constants (B=2, S=2048, H=1024, NH=8, HD=128)
static constexpr int Bz = 2;
static constexpr int Sq = 2048;
static constexpr int Hh = 1024;
static constexpr int NH = 8;
static constexpr int HD = 128;
static constexpr int H3 = 3072;
static constexpr int H6 = 6144;

// Workspace layout (floats). Total ~152.1 MB.
static constexpr size_t FUSED_OFF = 0;          // B*S*6H = 25,165,824
static constexpr size_t COMB_OFF  = 25165824;   // B*S*3H = 12,582,912
static constexpr size_t TAB_OFF   = 37748736;   // S*64 float2 = 262,144 floats
static constexpr size_t FLAG_OFF  = 38010880;   // 1 int

typedef float f32x4v __attribute__((ext_vector_type(4)));
typedef short s16x8 __attribute__((ext_vector_type(8)));

__device__ __forceinline__ float silu_(float x) { return x / (1.0f + expf(-x)); }

// f32 -> bf16 bits, round-to-nearest-even
__device__ __forceinline__ unsigned short f2bf(float x) {
  unsigned int u = __float_as_uint(x);
  u += 0x7fffu + ((u >> 16) & 1u);
  return (unsigned short)(u >> 16);
}

// ---------------- K0a: mask dtype detect. If any 32-bit word > 1, data is byte-packed bools.
__global__ __launch_bounds__(256) void hstu_mask_detect(const unsigned int* __restrict__ m,
                                                        int* __restrict__ flag) {
  __shared__ int s_any;
  if (threadIdx.x == 0) s_any = 0;
  __syncthreads();
  int any = 0;
  for (int i = threadIdx.x; i < 65536; i += 256)
    if (m[i] > 1u) any = 1;
  if (any) s_any = 1;  // benign race: all writers store 1
  __syncthreads();
  if (threadIdx.x == 0) *flag = s_any;
}

// ---------------- K0b: rope cos/sin table: tab[s*64+i] = {cos, sin}(s * 10000^(-i/64))
__global__ __launch_bounds__(256) void hstu_tab(float* __restrict__ tab) {
  int t = blockIdx.x * 256 + threadIdx.x;  // < S*64 = 131072
  int i = t & 63;
  int s = t >> 6;
  float inv = powf(10000.0f, -(float)i / 64.0f);
  float ang = (float)s * inv;
  float sn, cs;
  sincosf(ang, &sn, &cs);
  tab[2 * t + 0] = cs;
  tab[2 * t + 1] = sn;
}

// ---------------- K1: fused = silu(hidden @ W_qkvu)   M=4096 K=1024 N=6144  (fp32, unchanged)
__global__ __launch_bounds__(256) void hstu_gemm1(const float* __restrict__ A,
                                                  const float* __restrict__ Bw,
                                                  float* __restrict__ C) {
  constexpr int K = Hh, N = H6;
  __shared__ float As[8][128];
  __shared__ float Bs[8][128];
  const int tid = threadIdx.x;
  const int row0 = blockIdx.y * 128;
  const int col0 = blockIdx.x * 128;
  const int tx = tid & 15, ty = tid >> 4;
  float acc[8][8];
#pragma unroll
  for (int i = 0; i < 8; ++i)
#pragma unroll
    for (int j = 0; j < 8; ++j) acc[i][j] = 0.f;

  const int arow = tid >> 1, acol = (tid & 1) << 2;
  const int brow = tid >> 5, bcol = (tid & 31) << 2;
  for (int k0 = 0; k0 < K; k0 += 8) {
    float4 av = *(const float4*)&A[(size_t)(row0 + arow) * K + k0 + acol];
    As[acol + 0][arow] = av.x;
    As[acol + 1][arow] = av.y;
    As[acol + 2][arow] = av.z;
    As[acol + 3][arow] = av.w;
    *(float4*)&Bs[brow][bcol] = *(const float4*)&Bw[(size_t)(k0 + brow) * N + col0 + bcol];
    __syncthreads();
#pragma unroll
    for (int kk = 0; kk < 8; ++kk) {
      float4 a0 = *(const float4*)&As[kk][ty * 8];
      float4 a1 = *(const float4*)&As[kk][ty * 8 + 4];
      float4 b0 = *(const float4*)&Bs[kk][tx * 8];
      float4 b1 = *(const float4*)&Bs[kk][tx * 8 + 4];
      float a_[8] = {a0.x, a0.y, a0.z, a0.w, a1.x, a1.y, a1.z, a1.w};
      float b_[8] = {b0.x, b0.y, b0.z, b0.w, b1.x, b1.y, b1.z, b1.w};
#pragma unroll
      for (int i = 0; i < 8; ++i)
#pragma unroll
        for (int j = 0; j < 8; ++j) acc[i][j] += a_[i] * b_[j];
    }
    __syncthreads();
  }
#pragma unroll
  for (int i = 0; i < 8; ++i) {
    const size_t crow = (size_t)(row0 + ty * 8 + i) * N + col0 + tx * 8;
#pragma unroll
    for (int jq = 0; jq < 2; ++jq) {
      float4 o;
      o.x = silu_(acc[i][jq * 4 + 0]);
      o.y = silu_(acc[i][jq * 4 + 1]);
      o.z = silu_(acc[i][jq * 4 + 2]);
      o.w = silu_(acc[i][jq * 4 + 3]);
      *(float4*)&C[crow + jq * 4] = o;
    }
  }
}

// ---------------- K2: fused attention, bf16 MFMA (16x16x32).
// Block: (b, h, 32 q-rows). 4 waves. KVBLK=32.
// Scores: waves 0-1 plain (row-half 0/1), waves 2-3 rope. PV: wave w owns D-col quarter w.
// comb layout: [b][n][h*384 + {0:rope | 128:ts | 256:plain} + d]
__global__ __launch_bounds__(256) void hstu_attn(const float* __restrict__ fused,
                                                 const float2* __restrict__ tab,
                                                 const int* __restrict__ mask32,
                                                 const unsigned char* __restrict__ mask8,
                                                 const int* __restrict__ mflag,
                                                 const float* __restrict__ bias,
                                                 float* __restrict__ comb) {
  __shared__ __align__(16) unsigned short Qs[32][136];
  __shared__ __align__(16) unsigned short QRs[32][136];
  __shared__ __align__(16) unsigned short Ks[32][136];
  __shared__ __align__(16) unsigned short KRs[32][136];
  __shared__ __align__(16) unsigned short Vt[128][40];  // Vt[dd][m]
  __shared__ __align__(16) unsigned short Pl[3][32][40]; // 0=plain 1=rope 2=ts(bias)
  __shared__ float mtile[32][36];

  const int tid = threadIdx.x;
  const int lane = tid & 63;
  const int wid = tid >> 6;
  const int lo4 = lane & 15;
  const int hi2 = lane >> 4;  // 0..3
  const int n0 = blockIdx.x * 32;
  const int h = blockIdx.y;
  const int b = blockIdx.z;
  const float inv_s = 1.0f / 2048.0f;
  const int m_u8 = *mflag;  // uniform

  // ---- stage Q + roped Q (32 rows x 128) as bf16
  {
    const int row = tid >> 3;
    const int colg = (tid & 7) << 4;
    const float* qsrc = &fused[(size_t)(b * Sq + n0 + row) * H6 + 4 * Hh + h * HD + colg];
    const float2* trow = &tab[(size_t)(n0 + row) * 64];
#pragma unroll
    for (int c4 = 0; c4 < 4; ++c4) {
      const int col = colg + c4 * 4;
      float4 qv = *(const float4*)&qsrc[c4 * 4];
      float2 t0 = trow[col >> 1];
      float2 t1 = trow[(col >> 1) + 1];
      ushort4 qb, qrb;
      qb.x = f2bf(qv.x); qb.y = f2bf(qv.y); qb.z = f2bf(qv.z); qb.w = f2bf(qv.w);
      qrb.x = f2bf(qv.x * t0.x - qv.y * t0.y);
      qrb.y = f2bf(qv.y * t0.x + qv.x * t0.y);
      qrb.z = f2bf(qv.z * t1.x - qv.w * t1.y);
      qrb.w = f2bf(qv.w * t1.x + qv.z * t1.y);
      *(ushort4*)&Qs[row][col] = qb;
      *(ushort4*)&QRs[row][col] = qrb;
    }
  }
  __syncthreads();

  // hoist this wave's Q fragments (score A-operand): 4 d-chunks of K=32
  const int t_w = wid >> 1;   // 0=plain, 1=rope (score type for this wave)
  const int rh = wid & 1;     // row-half for scores
  s16x8 qf[4];
  {
    const unsigned short(*Qsrc)[136] = t_w ? QRs : Qs;
#pragma unroll
    for (int c = 0; c < 4; ++c)
      qf[c] = *(const s16x8*)&Qsrc[rh * 16 + lo4][c * 32 + hi2 * 8];
  }

  const f32x4v zero4 = {0.f, 0.f, 0.f, 0.f};
  f32x4v accO[3][2][2];  // [type][row-tile][col-tile within this wave's quarter]
#pragma unroll
  for (int t = 0; t < 3; ++t)
#pragma unroll
    for (int rt = 0; rt < 2; ++rt)
#pragma unroll
      for (int ct = 0; ct < 2; ++ct) accO[t][rt][ct] = zero4;

  for (int m0 = 0; m0 < Sq; m0 += 32) {
    __syncthreads();  // prev PV reads done before restaging
    // ---- stage K + roped K (32 rows x 128) bf16
    {
      const int row = tid >> 3;
      const int colg = (tid & 7) << 4;
      const float* ksrc = &fused[(size_t)(b * Sq + m0 + row) * H6 + 5 * Hh + h * HD + colg];
      const float2* trow = &tab[(size_t)(m0 + row) * 64];
#pragma unroll
      for (int c4 = 0; c4 < 4; ++c4) {
        const int col = colg + c4 * 4;
        float4 kv = *(const float4*)&ksrc[c4 * 4];
        float2 t0 = trow[col >> 1];
        float2 t1 = trow[(col >> 1) + 1];
        ushort4 kb, krb;
        kb.x = f2bf(kv.x); kb.y = f2bf(kv.y); kb.z = f2bf(kv.z); kb.w = f2bf(kv.w);
        krb.x = f2bf(kv.x * t0.x - kv.y * t0.y);
        krb.y = f2bf(kv.y * t0.x + kv.x * t0.y);
        krb.z = f2bf(kv.z * t1.x - kv.w * t1.y);
        krb.w = f2bf(kv.w * t1.x + kv.z * t1.y);
        *(ushort4*)&Ks[row][col] = kb;
        *(ushort4*)&KRs[row][col] = krb;
      }
    }
    // ---- stage V transposed: Vt[dd][m] bf16 (pairs of m packed as u32)
    {
      const int mp = (tid & 15) << 1;        // m0..m0+1 pair
      const int ddg = (tid >> 4) << 3;       // 8 dd values
      const float* v0 = &fused[(size_t)(b * Sq + m0 + mp) * H6 + 3 * Hh + h * HD + ddg];
      const float* v1 = v0 + H6;
      float4 a0 = *(const float4*)&v0[0];
      float4 a1 = *(const float4*)&v0[4];
      float4 b0 = *(const float4*)&v1[0];
      float4 b1 = *(const float4*)&v1[4];
      float va[8] = {a0.x, a0.y, a0.z, a0.w, a1.x, a1.y, a1.z, a1.w};
      float vb[8] = {b0.x, b0.y, b0.z, b0.w, b1.x, b1.y, b1.z, b1.w};
#pragma unroll
      for (int i = 0; i < 8; ++i) {
        unsigned int pk = (unsigned int)f2bf(va[i]) | ((unsigned int)f2bf(vb[i]) << 16);
        *(unsigned int*)&Vt[ddg + i][mp] = pk;
      }
    }
    // ---- stage mask tile (f32 0/1) + ts scores (masked bias, bf16)
    {
      const int row = tid >> 3;
      const int mg = (tid & 7) << 2;
      const size_t ibase = (size_t)(b * Sq + n0 + row) * Sq + m0 + mg;
      int mk[4];
      if (m_u8) {
        uchar4 mu = *(const uchar4*)&mask8[ibase];
        mk[0] = mu.x; mk[1] = mu.y; mk[2] = mu.z; mk[3] = mu.w;
      } else {
        int4 mi = *(const int4*)&mask32[ibase];
        mk[0] = mi.x; mk[1] = mi.y; mk[2] = mi.z; mk[3] = mi.w;
      }
      float4 bv = *(const float4*)&bias[ibase];
      float bb[4] = {bv.x, bv.y, bv.z, bv.w};
      ushort4 tsb;
      unsigned short* tp = (unsigned short*)&tsb;
      float4 mt;
      float* mp_ = (float*)&mt;
#pragma unroll
      for (int i = 0; i < 4; ++i) {
        mp_[i] = mk[i] ? 1.0f : 0.0f;
        tp[i] = f2bf(mk[i] ? bb[i] : 0.0f);
      }
      *(float4*)&mtile[row][mg] = mt;
      *(ushort4*)&Pl[2][row][mg] = tsb;
    }
    __syncthreads();
    // ---- scores: wave (t_w, rh) computes S[16 x 32], 2 m-tiles x 4 d-chunks
    {
      const unsigned short(*Kmat)[136] = t_w ? KRs : Ks;
#pragma unroll
      for (int mt = 0; mt < 2; ++mt) {
        f32x4v a = zero4;
#pragma unroll
        for (int c = 0; c < 4; ++c) {
          s16x8 kf = *(const s16x8*)&Kmat[mt * 16 + lo4][c * 32 + hi2 * 8];
          a = __builtin_amdgcn_mfma_f32_16x16x32_bf16(qf[c], kf, a, 0, 0, 0);
        }
#pragma unroll
        for (int r = 0; r < 4; ++r) {
          const int n = rh * 16 + hi2 * 4 + r;
          const int m = mt * 16 + lo4;
          float val = fmaxf(a[r], 0.f) * inv_s * mtile[n][m];
          Pl[t_w][n][m] = f2bf(val);
        }
      }
    }
    __syncthreads();
    // ---- PV: wave owns D-col quarter cq=wid: O[32][32] x 3 types
    {
      const int cq = wid;
      s16x8 af[3][2];
#pragma unroll
      for (int t = 0; t < 3; ++t)
#pragma unroll
        for (int rt = 0; rt < 2; ++rt)
          af[t][rt] = *(const s16x8*)&Pl[t][rt * 16 + lo4][hi2 * 8];
      s16x8 bf[2];
#pragma unroll
      for (int ct = 0; ct < 2; ++ct)
        bf[ct] = *(const s16x8*)&Vt[cq * 32 + ct * 16 + lo4][hi2 * 8];
#pragma unroll
      for (int t = 0; t < 3; ++t)
#pragma unroll
        for (int rt = 0; rt < 2; ++rt)
#pragma unroll
          for (int ct = 0; ct < 2; ++ct)
            accO[t][rt][ct] =
                __builtin_amdgcn_mfma_f32_16x16x32_bf16(af[t][rt], bf[ct], accO[t][rt][ct], 0, 0, 0);
    }
  }

  // ---- epilogue: comb offsets per type: plain->256, rope->0, ts->128
  const int toff[3] = {256, 0, 128};
  const int cq = wid;
#pragma unroll
  for (int t = 0; t < 3; ++t)
#pragma unroll
    for (int rt = 0; rt < 2; ++rt)
#pragma unroll
      for (int ct = 0; ct < 2; ++ct)
#pragma unroll
        for (int r = 0; r < 4; ++r) {
          const int n = n0 + rt * 16 + hi2 * 4 + r;
          const int dd = cq * 32 + ct * 16 + lo4;
          comb[(size_t)(b * Sq + n) * H3 + h * 384 + toff[t] + dd] = accO[t][rt][ct][r];
        }
}

// ---------------- K3: out = (comb*gated) @ W_out + b_out + hidden   M=4096 K=3072 N=1024
__global__ __launch_bounds__(256) void hstu_gemm2(const float* __restrict__ comb,
                                                  const float* __restrict__ fused,
                                                  const float* __restrict__ Bw,
                                                  const float* __restrict__ bout,
                                                  const float* __restrict__ hidden,
                                                  float* __restrict__ C) {
  constexpr int K = H3, N = Hh;
  __shared__ float As[8][128];
  __shared__ float Bs[8][128];
  const int tid = threadIdx.x;
  const int row0 = blockIdx.y * 128;
  const int col0 = blockIdx.x * 128;
  const int tx = tid & 15, ty = tid >> 4;
  float acc[8][8];
#pragma unroll
  for (int i = 0; i < 8; ++i)
#pragma unroll
    for (int j = 0; j < 8; ++j) acc[i][j] = 0.f;

  const int arow = tid >> 1, acol = (tid & 1) << 2;
  const int brow = tid >> 5, bcol = (tid & 31) << 2;
  for (int k0 = 0; k0 < K; k0 += 8) {
    const size_t am = (size_t)(row0 + arow);
    float4 c4 = *(const float4*)&comb[am * H3 + k0 + acol];
    float4 g4 = *(const float4*)&fused[am * H6 + k0 + acol];  // gated = fused[:, :3H]
    As[acol + 0][arow] = c4.x * g4.x;
    As[acol + 1][arow] = c4.y * g4.y;
    As[acol + 2][arow] = c4.z * g4.z;
    As[acol + 3][arow] = c4.w * g4.w;
    *(float4*)&Bs[brow][bcol] = *(const float4*)&Bw[(size_t)(k0 + brow) * N + col0 + bcol];
    __syncthreads();
#pragma unroll
    for (int kk = 0; kk < 8; ++kk) {
      float4 a0 = *(const float4*)&As[kk][ty * 8];
      float4 a1 = *(const float4*)&As[kk][ty * 8 + 4];
      float4 b0 = *(const float4*)&Bs[kk][tx * 8];
      float4 b1 = *(const float4*)&Bs[kk][tx * 8 + 4];
      float a_[8] = {a0.x, a0.y, a0.z, a0.w, a1.x, a1.y, a1.z, a1.w};
      float b_[8] = {b0.x, b0.y, b0.z, b0.w, b1.x, b1.y, b1.z, b1.w};
#pragma unroll
      for (int i = 0; i < 8; ++i)
#pragma unroll
        for (int j = 0; j < 8; ++j) acc[i][j] += a_[i] * b_[j];
    }
    __syncthreads();
  }
  float4 bo[2];
  bo[0] = *(const float4*)&bout[col0 + tx * 8];
  bo[1] = *(const float4*)&bout[col0 + tx * 8 + 4];
#pragma unroll
  for (int i = 0; i < 8; ++i) {
    const int gr = row0 + ty * 8 + i;
    const size_t crow = (size_t)gr * N + col0 + tx * 8;
#pragma unroll
    for (int jq = 0; jq < 2; ++jq) {
      float4 hd = *(const float4*)&hidden[crow + jq * 4];
      float4 o;
      o.x = acc[i][jq * 4 + 0] + bo[jq].x + hd.x;
      o.y = acc[i][jq * 4 + 1] + bo[jq].y + hd.y;
      o.z = acc[i][jq * 4 + 2] + bo[jq].z + hd.z;
      o.w = acc[i][jq * 4 + 3] + bo[jq].w + hd.w;
      *(float4*)&C[crow + jq * 4] = o;
    }
  }
}

// ---------------- K4: in-place RMS norm per row of d_out (4096 rows x 1024)
__global__ __launch_bounds__(256) void hstu_rms(float* __restrict__ y,
                                                const float* __restrict__ w) {
  __shared__ float red[4];
  const int row = blockIdx.x;
  const int tid = threadIdx.x;
  float4 v = *(float4*)&y[(size_t)row * Hh + tid * 4];
  float ss = v.x * v.x + v.y * v.y + v.z * v.z + v.w * v.w;
#pragma unroll
  for (int o = 32; o > 0; o >>= 1) ss += __shfl_down(ss, o);
  if ((tid & 63) == 0) red[tid >> 6] = ss;
  __syncthreads();
  const float tot = red[0] + red[1] + red[2] + red[3];
  const float r = 1.0f / sqrtf(tot / (float)Hh + 1e-6f);
  float4 wv = *(const float4*)&w[tid * 4];
  v.x *= r * wv.x;
  v.y *= r * wv.y;
  v.z *= r * wv.z;
  v.w *= r * wv.w;
  *(float4*)&y[(size_t)row * Hh + tid * 4] = v;
}

extern "C" void kernel_launch(void* const* d_in, const int* in_sizes, int n_in,
                              void* d_out, int out_size, void* d_ws, size_t ws_size,
                              hipStream_t stream) {
  const float* hidden = (const float*)d_in[0];
  const void* mask = d_in[1];                // bool mask: int32 or uint8 (detected)
  const float* bias = (const float*)d_in[2];
  const float* Wqkvu = (const float*)d_in[3];
  const float* Wout = (const float*)d_in[4];
  const float* bout = (const float*)d_in[5];
  const float* rmsw = (const float*)d_in[6];
  float* out = (float*)d_out;
  float* ws = (float*)d_ws;  // needs >= ~152.1 MB

  float* fused = ws + FUSED_OFF;
  float* comb = ws + COMB_OFF;
  float* tab = ws + TAB_OFF;
  int* mflag = (int*)(ws + FLAG_OFF);

  hstu_mask_detect<<<1, 256, 0, stream>>>((const unsigned int*)mask, mflag);
  hstu_tab<<<512, 256, 0, stream>>>(tab);
  hstu_gemm1<<<dim3(H6 / 128, (Bz * Sq) / 128), 256, 0, stream>>>(hidden, Wqkvu, fused);
  hstu_attn<<<dim3(Sq / 32, NH, Bz), 256, 0, stream>>>(
      fused, (const float2*)tab, (const int*)mask, (const unsigned char*)mask, mflag, bias, comb);
  hstu_gemm2<<<dim3(Hh / 128, (Bz * Sq) / 128), 256, 0, stream>>>(comb, fused, Wout, bout, hidden, out);
  hstu_rms<<<Bz * Sq, 256, 0, stream>>>(out, rmsw);
}

// Round 4
// 494.450 us; speedup vs baseline: 6.5218x; 3.3143x over previous
//
#include <hip/hip_runtime.h>
#include <math.h>

// Problem constants (B=2, S=2048, H=1024, NH=8, HD=128)
static constexpr int Bz = 2;
static constexpr int Sq = 2048;
static constexpr int Hh = 1024;
static constexpr int NH = 8;
static constexpr int HD = 128;
static constexpr int H3 = 3072;
static constexpr int H6 = 6144;

typedef unsigned short ushort_t;
typedef float f32x4v __attribute__((ext_vector_type(4)));
typedef short s16x8 __attribute__((ext_vector_type(8)));

// Workspace layout in float units (×4 bytes). Total ~129 MB.
static constexpr size_t FUSED_OFF = 0;          // bf16 [4096][6144] = 12,582,912 f
static constexpr size_t COMB_OFF  = 12582912;   // bf16 [4096][3072] =  6,291,456 f
static constexpr size_t A2_OFF    = 18874368;   // bf16 [4096][3072] =  6,291,456 f
static constexpr size_t HB_OFF    = 25165824;   // bf16 [4096][1024] =  2,097,152 f
static constexpr size_t WQT_OFF   = 27262976;   // bf16 [6144][1024] =  3,145,728 f
static constexpr size_t WOT_OFF   = 30408704;   // bf16 [1024][3072] =  1,572,864 f
static constexpr size_t TAB_OFF   = 31981568;   // f32 S*64 float2 = 262,144 f
static constexpr size_t FLAG_OFF  = 32243712;   // 1 int

__device__ __forceinline__ float silu_(float x) { return x / (1.0f + expf(-x)); }
__device__ __forceinline__ ushort_t f2bf(float x) {
  unsigned int u = __float_as_uint(x);
  u += 0x7fffu + ((u >> 16) & 1u);
  return (ushort_t)(u >> 16);
}
__device__ __forceinline__ float bf2f(ushort_t u) {
  return __uint_as_float(((unsigned int)u) << 16);
}
// async global->LDS 16B: per-lane global src, wave-uniform LDS base (+lane*16B by HW)
__device__ __forceinline__ void g2l16(const ushort_t* g, ushort_t* l) {
  __builtin_amdgcn_global_load_lds(
      (const __attribute__((address_space(1))) unsigned int*)g,
      (__attribute__((address_space(3))) unsigned int*)l, 16, 0, 0);
}

// ---------------- mask dtype detect: any 32-bit word > 1 => byte-packed bools
__global__ __launch_bounds__(256) void hstu_mask_detect(const unsigned int* __restrict__ m,
                                                        int* __restrict__ flag) {
  __shared__ int s_any;
  if (threadIdx.x == 0) s_any = 0;
  __syncthreads();
  int any = 0;
  for (int i = threadIdx.x; i < 65536; i += 256)
    if (m[i] > 1u) any = 1;
  if (any) s_any = 1;
  __syncthreads();
  if (threadIdx.x == 0) *flag = s_any;
}

// ---------------- rope table: tab[s*64+i] = {cos,sin}(s * 10000^(-i/64))
__global__ __launch_bounds__(256) void hstu_tab(float* __restrict__ tab) {
  int t = blockIdx.x * 256 + threadIdx.x;
  int i = t & 63;
  int s = t >> 6;
  float inv = powf(10000.0f, -(float)i / 64.0f);
  float sn, cs;
  sincosf((float)s * inv, &sn, &cs);
  tab[2 * t + 0] = cs;
  tab[2 * t + 1] = sn;
}

// ---------------- f32 -> bf16 row-major copy (hidden)
__global__ __launch_bounds__(256) void hstu_cvt(const float* __restrict__ in,
                                                ushort_t* __restrict__ out, int n4) {
  int i = blockIdx.x * 256 + threadIdx.x;
  if (i >= n4) return;
  float4 v = *(const float4*)&in[(size_t)i * 4];
  ushort4 o;
  o.x = f2bf(v.x); o.y = f2bf(v.y); o.z = f2bf(v.z); o.w = f2bf(v.w);
  *(ushort4*)&out[(size_t)i * 4] = o;
}

// ---------------- f32 [K][N] -> bf16 [N][K] transpose-convert (weights)
__global__ __launch_bounds__(256) void hstu_cvt_t(const float* __restrict__ in,
                                                  ushort_t* __restrict__ out, int K, int N) {
  __shared__ float t[32][33];
  const int n0 = blockIdx.x * 32, k0 = blockIdx.y * 32;
  const int c = threadIdx.x & 31, rr = threadIdx.x >> 5;  // 8 rows/pass
#pragma unroll
  for (int p = 0; p < 4; ++p)
    t[rr + p * 8][c] = in[(size_t)(k0 + rr + p * 8) * N + n0 + c];
  __syncthreads();
#pragma unroll
  for (int p = 0; p < 4; ++p)
    out[(size_t)(n0 + rr + p * 8) * K + k0 + c] = f2bf(t[c][rr + p * 8]);
}

// ---------------- GEMM1: fused = silu(hidden_bf @ WqT^T)  M=4096 N=6144 K=1024, bf16 out
__global__ __launch_bounds__(256) void hstu_gemm_silu(const ushort_t* __restrict__ A,
                                                      const ushort_t* __restrict__ Bt,
                                                      ushort_t* __restrict__ C) {
  constexpr int K = 1024, N = H6;
  __shared__ ushort_t As[128 * 64];
  __shared__ ushort_t Bs[128 * 64];
  const int tid = threadIdx.x, lane = tid & 63, wid = tid >> 6;
  const int lo4 = lane & 15, hi2 = lane >> 4;
  const int wr = wid >> 1, wc = wid & 1;
  const int row0 = blockIdx.y * 128, col0 = blockIdx.x * 128;
  const int srow = lane >> 3, scol = (lane & 7) * 8;
  f32x4v acc[4][4];
#pragma unroll
  for (int i = 0; i < 4; ++i)
#pragma unroll
    for (int j = 0; j < 4; ++j) acc[i][j] = {0.f, 0.f, 0.f, 0.f};

  for (int k0 = 0; k0 < K; k0 += 64) {
    __syncthreads();
#pragma unroll
    for (int i = 0; i < 4; ++i) {
      const int rb = wid * 32 + i * 8;
      g2l16(&A[(size_t)(row0 + rb + srow) * K + k0 + scol], &As[rb * 64]);
      g2l16(&Bt[(size_t)(col0 + rb + srow) * K + k0 + scol], &Bs[rb * 64]);
    }
    __syncthreads();
#pragma unroll
    for (int kc = 0; kc < 2; ++kc) {
      s16x8 af[4], bfr[4];
#pragma unroll
      for (int mi = 0; mi < 4; ++mi)
        af[mi] = *(const s16x8*)&As[(wr * 64 + mi * 16 + lo4) * 64 + kc * 32 + hi2 * 8];
#pragma unroll
      for (int nj = 0; nj < 4; ++nj)
        bfr[nj] = *(const s16x8*)&Bs[(wc * 64 + nj * 16 + lo4) * 64 + kc * 32 + hi2 * 8];
#pragma unroll
      for (int mi = 0; mi < 4; ++mi)
#pragma unroll
        for (int nj = 0; nj < 4; ++nj)
          acc[mi][nj] = __builtin_amdgcn_mfma_f32_16x16x32_bf16(af[mi], bfr[nj], acc[mi][nj], 0, 0, 0);
    }
  }
#pragma unroll
  for (int mi = 0; mi < 4; ++mi)
#pragma unroll
    for (int nj = 0; nj < 4; ++nj)
#pragma unroll
      for (int r = 0; r < 4; ++r) {
        const int row = row0 + wr * 64 + mi * 16 + hi2 * 4 + r;
        const int col = col0 + wc * 64 + nj * 16 + lo4;
        C[(size_t)row * N + col] = f2bf(silu_(acc[mi][nj][r]));
      }
}

// ---------------- GEMM2: out = A2 @ WoT^T + b_out + hidden  M=4096 N=1024 K=3072, f32 out
__global__ __launch_bounds__(256) void hstu_gemm_out(const ushort_t* __restrict__ A,
                                                     const ushort_t* __restrict__ Bt,
                                                     const float* __restrict__ bout,
                                                     const float* __restrict__ hidden,
                                                     float* __restrict__ C) {
  constexpr int K = H3, N = Hh;
  __shared__ ushort_t As[128 * 64];
  __shared__ ushort_t Bs[64 * 64];
  const int tid = threadIdx.x, lane = tid & 63, wid = tid >> 6;
  const int lo4 = lane & 15, hi2 = lane >> 4;
  const int wr = wid >> 1, wc = wid & 1;
  const int row0 = blockIdx.y * 128, col0 = blockIdx.x * 64;
  const int srow = lane >> 3, scol = (lane & 7) * 8;
  f32x4v acc[4][2];
#pragma unroll
  for (int i = 0; i < 4; ++i)
#pragma unroll
    for (int j = 0; j < 2; ++j) acc[i][j] = {0.f, 0.f, 0.f, 0.f};

  for (int k0 = 0; k0 < K; k0 += 64) {
    __syncthreads();
#pragma unroll
    for (int i = 0; i < 4; ++i) {
      const int rb = wid * 32 + i * 8;
      g2l16(&A[(size_t)(row0 + rb + srow) * K + k0 + scol], &As[rb * 64]);
    }
#pragma unroll
    for (int i = 0; i < 2; ++i) {
      const int rb = wid * 16 + i * 8;
      g2l16(&Bt[(size_t)(col0 + rb + srow) * K + k0 + scol], &Bs[rb * 64]);
    }
    __syncthreads();
#pragma unroll
    for (int kc = 0; kc < 2; ++kc) {
      s16x8 af[4], bfr[2];
#pragma unroll
      for (int mi = 0; mi < 4; ++mi)
        af[mi] = *(const s16x8*)&As[(wr * 64 + mi * 16 + lo4) * 64 + kc * 32 + hi2 * 8];
#pragma unroll
      for (int nj = 0; nj < 2; ++nj)
        bfr[nj] = *(const s16x8*)&Bs[(wc * 32 + nj * 16 + lo4) * 64 + kc * 32 + hi2 * 8];
#pragma unroll
      for (int mi = 0; mi < 4; ++mi)
#pragma unroll
        for (int nj = 0; nj < 2; ++nj)
          acc[mi][nj] = __builtin_amdgcn_mfma_f32_16x16x32_bf16(af[mi], bfr[nj], acc[mi][nj], 0, 0, 0);
    }
  }
#pragma unroll
  for (int mi = 0; mi < 4; ++mi)
#pragma unroll
    for (int nj = 0; nj < 2; ++nj)
#pragma unroll
      for (int r = 0; r < 4; ++r) {
        const int row = row0 + wr * 64 + mi * 16 + hi2 * 4 + r;
        const int col = col0 + wc * 32 + nj * 16 + lo4;
        C[(size_t)row * N + col] = acc[mi][nj][r] + bout[col] + hidden[(size_t)row * N + col];
      }
}

// ---------------- A2 = comb .* gated (bf16 elementwise), 4096 x 3072
__global__ __launch_bounds__(256) void hstu_a2(const ushort_t* __restrict__ comb,
                                               const ushort_t* __restrict__ fused,
                                               ushort_t* __restrict__ A2) {
  const int c = blockIdx.x * 256 + threadIdx.x;  // over 4096*3072/8 = 1,572,864 chunks
  const int m = c / 384;
  const int j = (c - m * 384) * 8;
  s16x8 cv = *(const s16x8*)&comb[(size_t)m * H3 + j];
  s16x8 gv = *(const s16x8*)&fused[(size_t)m * H6 + j];
  ushort_t r[8];
#pragma unroll
  for (int i = 0; i < 8; ++i)
    r[i] = f2bf(bf2f((ushort_t)cv[i]) * bf2f((ushort_t)gv[i]));
  *(s16x8*)&A2[(size_t)m * H3 + j] = *(s16x8*)r;
}

// ---------------- fused attention, bf16 MFMA. Block: (b,h,32 q-rows), KVBLK=32, 4 waves.
// comb layout: [b][n][h*384 + {0:rope | 128:ts | 256:plain} + d], bf16
__global__ __launch_bounds__(256) void hstu_attn(const ushort_t* __restrict__ fused,
                                                 const float2* __restrict__ tab,
                                                 const int* __restrict__ mask32,
                                                 const unsigned char* __restrict__ mask8,
                                                 const int* __restrict__ mflag,
                                                 const float* __restrict__ bias,
                                                 ushort_t* __restrict__ comb) {
  __shared__ __align__(16) ushort_t Qs[32][136];
  __shared__ __align__(16) ushort_t QRs[32][136];
  __shared__ __align__(16) ushort_t Ks[32][136];
  __shared__ __align__(16) ushort_t KRs[32][136];
  __shared__ __align__(16) ushort_t Vt[128][40];   // Vt[dd][m]
  __shared__ __align__(16) ushort_t Pl[3][32][40]; // 0=plain 1=rope 2=ts
  __shared__ float mtile[32][36];

  const int tid = threadIdx.x;
  const int lane = tid & 63;
  const int wid = tid >> 6;
  const int lo4 = lane & 15;
  const int hi2 = lane >> 4;
  const int n0 = blockIdx.x * 32;
  const int h = blockIdx.y;
  const int b = blockIdx.z;
  const float inv_s = 1.0f / 2048.0f;
  const int m_u8 = *mflag;

  // ---- stage Q + roped Q (32 x 128) bf16
  {
    const int row = tid >> 3;
    const int colg = (tid & 7) << 4;
    const ushort_t* qsrc = &fused[(size_t)(b * Sq + n0 + row) * H6 + 4 * Hh + h * HD + colg];
    const float2* trow = &tab[(size_t)(n0 + row) * 64 + (colg >> 1)];
#pragma unroll
    for (int c8 = 0; c8 < 2; ++c8) {
      s16x8 us = *(const s16x8*)&qsrc[c8 * 8];
      *(s16x8*)&Qs[row][colg + c8 * 8] = us;
      ushort_t ro[8];
#pragma unroll
      for (int p = 0; p < 4; ++p) {
        float x = bf2f((ushort_t)us[2 * p]), y = bf2f((ushort_t)us[2 * p + 1]);
        float2 t = trow[c8 * 4 + p];
        ro[2 * p] = f2bf(x * t.x - y * t.y);
        ro[2 * p + 1] = f2bf(y * t.x + x * t.y);
      }
      *(s16x8*)&QRs[row][colg + c8 * 8] = *(s16x8*)ro;
    }
  }
  __syncthreads();

  const int t_w = wid >> 1;  // 0=plain 1=rope
  const int rh = wid & 1;
  s16x8 qf[4];
  {
    const ushort_t(*Qsrc)[136] = t_w ? QRs : Qs;
#pragma unroll
    for (int c = 0; c < 4; ++c)
      qf[c] = *(const s16x8*)&Qsrc[rh * 16 + lo4][c * 32 + hi2 * 8];
  }

  const f32x4v zero4 = {0.f, 0.f, 0.f, 0.f};
  f32x4v accO[3][2][2];
#pragma unroll
  for (int t = 0; t < 3; ++t)
#pragma unroll
    for (int rt = 0; rt < 2; ++rt)
#pragma unroll
      for (int ct = 0; ct < 2; ++ct) accO[t][rt][ct] = zero4;

  for (int m0 = 0; m0 < Sq; m0 += 32) {
    __syncthreads();
    // ---- stage K + roped K
    {
      const int row = tid >> 3;
      const int colg = (tid & 7) << 4;
      const ushort_t* ksrc = &fused[(size_t)(b * Sq + m0 + row) * H6 + 5 * Hh + h * HD + colg];
      const float2* trow = &tab[(size_t)(m0 + row) * 64 + (colg >> 1)];
#pragma unroll
      for (int c8 = 0; c8 < 2; ++c8) {
        s16x8 us = *(const s16x8*)&ksrc[c8 * 8];
        *(s16x8*)&Ks[row][colg + c8 * 8] = us;
        ushort_t ro[8];
#pragma unroll
        for (int p = 0; p < 4; ++p) {
          float x = bf2f((ushort_t)us[2 * p]), y = bf2f((ushort_t)us[2 * p + 1]);
          float2 t = trow[c8 * 4 + p];
          ro[2 * p] = f2bf(x * t.x - y * t.y);
          ro[2 * p + 1] = f2bf(y * t.x + x * t.y);
        }
        *(s16x8*)&KRs[row][colg + c8 * 8] = *(s16x8*)ro;
      }
    }
    // ---- stage V transposed (pack 2 m per u32)
    {
      const int mp = (tid & 15) << 1;
      const int ddg = (tid >> 4) << 3;
      const ushort_t* v0 = &fused[(size_t)(b * Sq + m0 + mp) * H6 + 3 * Hh + h * HD + ddg];
      const ushort_t* v1 = v0 + H6;
      s16x8 a = *(const s16x8*)v0;
      s16x8 bv = *(const s16x8*)v1;
#pragma unroll
      for (int i = 0; i < 8; ++i) {
        unsigned int pk = (unsigned int)(ushort_t)a[i] | ((unsigned int)(ushort_t)bv[i] << 16);
        *(unsigned int*)&Vt[ddg + i][mp] = pk;
      }
    }
    // ---- stage mask + ts scores
    {
      const int row = tid >> 3;
      const int mg = (tid & 7) << 2;
      const size_t ibase = (size_t)(b * Sq + n0 + row) * Sq + m0 + mg;
      int mk[4];
      if (m_u8) {
        uchar4 mu = *(const uchar4*)&mask8[ibase];
        mk[0] = mu.x; mk[1] = mu.y; mk[2] = mu.z; mk[3] = mu.w;
      } else {
        int4 mi = *(const int4*)&mask32[ibase];
        mk[0] = mi.x; mk[1] = mi.y; mk[2] = mi.z; mk[3] = mi.w;
      }
      float4 bv = *(const float4*)&bias[ibase];
      float bb[4] = {bv.x, bv.y, bv.z, bv.w};
      ushort4 tsb;
      ushort_t* tp = (ushort_t*)&tsb;
      float4 mt;
      float* mp_ = (float*)&mt;
#pragma unroll
      for (int i = 0; i < 4; ++i) {
        mp_[i] = mk[i] ? 1.0f : 0.0f;
        tp[i] = f2bf(mk[i] ? bb[i] : 0.0f);
      }
      *(float4*)&mtile[row][mg] = mt;
      *(ushort4*)&Pl[2][row][mg] = tsb;
    }
    __syncthreads();
    // ---- scores
    {
      const ushort_t(*Kmat)[136] = t_w ? KRs : Ks;
#pragma unroll
      for (int mt = 0; mt < 2; ++mt) {
        f32x4v a = zero4;
#pragma unroll
        for (int c = 0; c < 4; ++c) {
          s16x8 kf = *(const s16x8*)&Kmat[mt * 16 + lo4][c * 32 + hi2 * 8];
          a = __builtin_amdgcn_mfma_f32_16x16x32_bf16(qf[c], kf, a, 0, 0, 0);
        }
#pragma unroll
        for (int r = 0; r < 4; ++r) {
          const int n = rh * 16 + hi2 * 4 + r;
          const int m = mt * 16 + lo4;
          Pl[t_w][n][m] = f2bf(fmaxf(a[r], 0.f) * inv_s * mtile[n][m]);
        }
      }
    }
    __syncthreads();
    // ---- PV
    {
      const int cq = wid;
      s16x8 af[3][2];
#pragma unroll
      for (int t = 0; t < 3; ++t)
#pragma unroll
        for (int rt = 0; rt < 2; ++rt)
          af[t][rt] = *(const s16x8*)&Pl[t][rt * 16 + lo4][hi2 * 8];
      s16x8 bfv[2];
#pragma unroll
      for (int ct = 0; ct < 2; ++ct)
        bfv[ct] = *(const s16x8*)&Vt[cq * 32 + ct * 16 + lo4][hi2 * 8];
#pragma unroll
      for (int t = 0; t < 3; ++t)
#pragma unroll
        for (int rt = 0; rt < 2; ++rt)
#pragma unroll
          for (int ct = 0; ct < 2; ++ct)
            accO[t][rt][ct] =
                __builtin_amdgcn_mfma_f32_16x16x32_bf16(af[t][rt], bfv[ct], accO[t][rt][ct], 0, 0, 0);
    }
  }

  const int toff[3] = {256, 0, 128};
  const int cq = wid;
#pragma unroll
  for (int t = 0; t < 3; ++t)
#pragma unroll
    for (int rt = 0; rt < 2; ++rt)
#pragma unroll
      for (int ct = 0; ct < 2; ++ct)
#pragma unroll
        for (int r = 0; r < 4; ++r) {
          const int n = n0 + rt * 16 + hi2 * 4 + r;
          const int dd = cq * 32 + ct * 16 + lo4;
          comb[(size_t)(b * Sq + n) * H3 + h * 384 + toff[t] + dd] = f2bf(accO[t][rt][ct][r]);
        }
}

// ---------------- RMS norm in-place (4096 rows x 1024), f32
__global__ __launch_bounds__(256) void hstu_rms(float* __restrict__ y,
                                                const float* __restrict__ w) {
  __shared__ float red[4];
  const int row = blockIdx.x;
  const int tid = threadIdx.x;
  float4 v = *(float4*)&y[(size_t)row * Hh + tid * 4];
  float ss = v.x * v.x + v.y * v.y + v.z * v.z + v.w * v.w;
#pragma unroll
  for (int o = 32; o > 0; o >>= 1) ss += __shfl_down(ss, o);
  if ((tid & 63) == 0) red[tid >> 6] = ss;
  __syncthreads();
  const float tot = red[0] + red[1] + red[2] + red[3];
  const float r = 1.0f / sqrtf(tot / (float)Hh + 1e-6f);
  float4 wv = *(const float4*)&w[tid * 4];
  v.x *= r * wv.x;
  v.y *= r * wv.y;
  v.z *= r * wv.z;
  v.w *= r * wv.w;
  *(float4*)&y[(size_t)row * Hh + tid * 4] = v;
}

extern "C" void kernel_launch(void* const* d_in, const int* in_sizes, int n_in,
                              void* d_out, int out_size, void* d_ws, size_t ws_size,
                              hipStream_t stream) {
  const float* hidden = (const float*)d_in[0];
  const void* mask = d_in[1];
  const float* bias = (const float*)d_in[2];
  const float* Wqkvu = (const float*)d_in[3];
  const float* Wout = (const float*)d_in[4];
  const float* bout = (const float*)d_in[5];
  const float* rmsw = (const float*)d_in[6];
  float* out = (float*)d_out;
  float* ws = (float*)d_ws;

  ushort_t* fused = (ushort_t*)(ws + FUSED_OFF);
  ushort_t* comb = (ushort_t*)(ws + COMB_OFF);
  ushort_t* a2 = (ushort_t*)(ws + A2_OFF);
  ushort_t* hb = (ushort_t*)(ws + HB_OFF);
  ushort_t* wqt = (ushort_t*)(ws + WQT_OFF);
  ushort_t* wot = (ushort_t*)(ws + WOT_OFF);
  float* tab = ws + TAB_OFF;
  int* mflag = (int*)(ws + FLAG_OFF);

  hstu_mask_detect<<<1, 256, 0, stream>>>((const unsigned int*)mask, mflag);
  hstu_tab<<<512, 256, 0, stream>>>(tab);
  hstu_cvt<<<4096, 256, 0, stream>>>(hidden, hb, (Bz * Sq * Hh) / 4);
  hstu_cvt_t<<<dim3(H6 / 32, Hh / 32), 256, 0, stream>>>(Wqkvu, wqt, Hh, H6);
  hstu_cvt_t<<<dim3(Hh / 32, H3 / 32), 256, 0, stream>>>(Wout, wot, H3, Hh);
  hstu_gemm_silu<<<dim3(H6 / 128, (Bz * Sq) / 128), 256, 0, stream>>>(hb, wqt, fused);
  hstu_attn<<<dim3(Sq / 32, NH, Bz), 256, 0, stream>>>(
      fused, (const float2*)tab, (const int*)mask, (const unsigned char*)mask, mflag, bias, comb);
  hstu_a2<<<(Bz * Sq * H3 / 8) / 256, 256, 0, stream>>>(comb, fused, a2);
  hstu_gemm_out<<<dim3(Hh / 64, (Bz * Sq) / 128), 256, 0, stream>>>(a2, wot, bout, hidden, out);
  hstu_rms<<<Bz * Sq, 256, 0, stream>>>(out, rmsw);
}

// Round 5
// 388.843 us; speedup vs baseline: 8.2931x; 1.2716x over previous
//
#include <hip/hip_runtime.h>
#include <math.h>

// Problem constants (B=2, S=2048, H=1024, NH=8, HD=128)
static constexpr int Bz = 2;
static constexpr int Sq = 2048;
static constexpr int Hh = 1024;
static constexpr int NH = 8;
static constexpr int HD = 128;
static constexpr int H3 = 3072;
static constexpr int H6 = 6144;

typedef unsigned short ushort_t;
typedef float f32x4v __attribute__((ext_vector_type(4)));
typedef short s16x8 __attribute__((ext_vector_type(8)));

// Workspace layout in float units (×4 bytes). Total ~129 MB.
static constexpr size_t FUSED_OFF = 0;          // bf16 [4096][6144] = 12,582,912 f
static constexpr size_t A2_OFF    = 12582912;   // bf16 [4096][3072] =  6,291,456 f
static constexpr size_t HB_OFF    = 18874368;   // bf16 [4096][1024] =  2,097,152 f
static constexpr size_t WQT_OFF   = 20971520;   // bf16 [6144][1024] =  3,145,728 f
static constexpr size_t WOT_OFF   = 24117248;   // bf16 [1024][3072] =  1,572,864 f
static constexpr size_t QR_OFF    = 25690112;   // bf16 [4096][1024] =  2,097,152 f
static constexpr size_t KR_OFF    = 27787264;   // bf16 [4096][1024] =  2,097,152 f
static constexpr size_t VT_OFF    = 29884416;   // bf16 [16][128][2048] = 2,097,152 f
static constexpr size_t TAB_OFF   = 31981568;   // f32 S*64 float2 = 262,144 f
static constexpr size_t FLAG_OFF  = 32243712;   // 1 int

__device__ __forceinline__ float silu_(float x) { return x / (1.0f + expf(-x)); }
__device__ __forceinline__ ushort_t f2bf(float x) {
  unsigned int u = __float_as_uint(x);
  u += 0x7fffu + ((u >> 16) & 1u);
  return (ushort_t)(u >> 16);
}
__device__ __forceinline__ float bf2f(ushort_t u) {
  return __uint_as_float(((unsigned int)u) << 16);
}
// async global->LDS 16B: per-lane global src, wave-uniform LDS base (+lane*16B by HW)
__device__ __forceinline__ void g2l16(const ushort_t* g, ushort_t* l) {
  __builtin_amdgcn_global_load_lds(
      (const __attribute__((address_space(1))) unsigned int*)g,
      (__attribute__((address_space(3))) unsigned int*)l, 16, 0, 0);
}

// ---------------- mask dtype detect: any 32-bit word > 1 => byte-packed bools
__global__ __launch_bounds__(256) void hstu_mask_detect(const unsigned int* __restrict__ m,
                                                        int* __restrict__ flag) {
  __shared__ int s_any;
  if (threadIdx.x == 0) s_any = 0;
  __syncthreads();
  int any = 0;
  for (int i = threadIdx.x; i < 65536; i += 256)
    if (m[i] > 1u) any = 1;
  if (any) s_any = 1;
  __syncthreads();
  if (threadIdx.x == 0) *flag = s_any;
}

// ---------------- rope table: tab[s*64+i] = {cos,sin}(s * 10000^(-i/64))
__global__ __launch_bounds__(256) void hstu_tab(float* __restrict__ tab) {
  int t = blockIdx.x * 256 + threadIdx.x;
  int i = t & 63;
  int s = t >> 6;
  float inv = powf(10000.0f, -(float)i / 64.0f);
  float sn, cs;
  sincosf((float)s * inv, &sn, &cs);
  tab[2 * t + 0] = cs;
  tab[2 * t + 1] = sn;
}

// ---------------- f32 -> bf16 row-major copy (hidden)
__global__ __launch_bounds__(256) void hstu_cvt(const float* __restrict__ in,
                                                ushort_t* __restrict__ out, int n4) {
  int i = blockIdx.x * 256 + threadIdx.x;
  if (i >= n4) return;
  float4 v = *(const float4*)&in[(size_t)i * 4];
  ushort4 o;
  o.x = f2bf(v.x); o.y = f2bf(v.y); o.z = f2bf(v.z); o.w = f2bf(v.w);
  *(ushort4*)&out[(size_t)i * 4] = o;
}

// ---------------- f32 [K][N] -> bf16 [N][K] transpose-convert (weights)
__global__ __launch_bounds__(256) void hstu_cvt_t(const float* __restrict__ in,
                                                  ushort_t* __restrict__ out, int K, int N) {
  __shared__ float t[32][33];
  const int n0 = blockIdx.x * 32, k0 = blockIdx.y * 32;
  const int c = threadIdx.x & 31, rr = threadIdx.x >> 5;
#pragma unroll
  for (int p = 0; p < 4; ++p)
    t[rr + p * 8][c] = in[(size_t)(k0 + rr + p * 8) * N + n0 + c];
  __syncthreads();
#pragma unroll
  for (int p = 0; p < 4; ++p)
    out[(size_t)(n0 + rr + p * 8) * K + k0 + c] = f2bf(t[c][rr + p * 8]);
}

// ---------------- rope precompute: qr/kr[b][s][h*128+d] = rope(fused q/k), bf16
__global__ __launch_bounds__(256) void hstu_rope(const ushort_t* __restrict__ fused,
                                                 const float2* __restrict__ tab,
                                                 ushort_t* __restrict__ qr,
                                                 ushort_t* __restrict__ kr) {
  const int idx = blockIdx.x * 256 + threadIdx.x;  // over 4096*1024/8
  const int row = idx >> 7;
  const int cg = (idx & 127) * 8;
  const int s = row & (Sq - 1);
  const float2* trow = &tab[(size_t)s * 64 + ((cg & 127) >> 1)];
  float2 t[4];
#pragma unroll
  for (int p = 0; p < 4; ++p) t[p] = trow[p];

  s16x8 q8 = *(const s16x8*)&fused[(size_t)row * H6 + 4 * Hh + cg];
  s16x8 k8 = *(const s16x8*)&fused[(size_t)row * H6 + 5 * Hh + cg];
  ushort_t qo[8], ko[8];
#pragma unroll
  for (int p = 0; p < 4; ++p) {
    float qx = bf2f((ushort_t)q8[2 * p]), qy = bf2f((ushort_t)q8[2 * p + 1]);
    float kx = bf2f((ushort_t)k8[2 * p]), ky = bf2f((ushort_t)k8[2 * p + 1]);
    qo[2 * p] = f2bf(qx * t[p].x - qy * t[p].y);
    qo[2 * p + 1] = f2bf(qy * t[p].x + qx * t[p].y);
    ko[2 * p] = f2bf(kx * t[p].x - ky * t[p].y);
    ko[2 * p + 1] = f2bf(ky * t[p].x + kx * t[p].y);
  }
  *(s16x8*)&qr[(size_t)row * Hh + cg] = *(s16x8*)qo;
  *(s16x8*)&kr[(size_t)row * Hh + cg] = *(s16x8*)ko;
}

// ---------------- V transpose precompute: vt[(b*8+h)*128+dd][m] = V[b][m][h*128+dd]
__global__ __launch_bounds__(256) void hstu_vt(const ushort_t* __restrict__ fused,
                                               ushort_t* __restrict__ vt) {
  __shared__ ushort_t t[32][36];
  const int m0 = blockIdx.x * 32, d0 = blockIdx.y * 32, bh = blockIdx.z;
  const int b = bh >> 3, h = bh & 7;
  const int r = threadIdx.x >> 3, cg = (threadIdx.x & 7) * 4;
  *(ushort4*)&t[r][cg] =
      *(const ushort4*)&fused[(size_t)(b * Sq + m0 + r) * H6 + 3 * Hh + h * HD + d0 + cg];
  __syncthreads();
  ushort4 o;
  o.x = t[cg + 0][r]; o.y = t[cg + 1][r]; o.z = t[cg + 2][r]; o.w = t[cg + 3][r];
  *(ushort4*)&vt[(size_t)(bh * HD + d0 + r) * Sq + m0 + cg] = o;
}

// ---------------- GEMM1: fused = silu(hidden_bf @ WqT^T)  M=4096 N=6144 K=1024, bf16 out
__global__ __launch_bounds__(256) void hstu_gemm_silu(const ushort_t* __restrict__ A,
                                                      const ushort_t* __restrict__ Bt,
                                                      ushort_t* __restrict__ C) {
  constexpr int K = 1024, N = H6;
  __shared__ ushort_t As[128 * 64];
  __shared__ ushort_t Bs[128 * 64];
  const int tid = threadIdx.x, lane = tid & 63, wid = tid >> 6;
  const int lo4 = lane & 15, hi2 = lane >> 4;
  const int wr = wid >> 1, wc = wid & 1;
  const int row0 = blockIdx.y * 128, col0 = blockIdx.x * 128;
  const int srow = lane >> 3, scol = (lane & 7) * 8;
  f32x4v acc[4][4];
#pragma unroll
  for (int i = 0; i < 4; ++i)
#pragma unroll
    for (int j = 0; j < 4; ++j) acc[i][j] = {0.f, 0.f, 0.f, 0.f};

  for (int k0 = 0; k0 < K; k0 += 64) {
    __syncthreads();
#pragma unroll
    for (int i = 0; i < 4; ++i) {
      const int rb = wid * 32 + i * 8;
      g2l16(&A[(size_t)(row0 + rb + srow) * K + k0 + scol], &As[rb * 64]);
      g2l16(&Bt[(size_t)(col0 + rb + srow) * K + k0 + scol], &Bs[rb * 64]);
    }
    __syncthreads();
#pragma unroll
    for (int kc = 0; kc < 2; ++kc) {
      s16x8 af[4], bfr[4];
#pragma unroll
      for (int mi = 0; mi < 4; ++mi)
        af[mi] = *(const s16x8*)&As[(wr * 64 + mi * 16 + lo4) * 64 + kc * 32 + hi2 * 8];
#pragma unroll
      for (int nj = 0; nj < 4; ++nj)
        bfr[nj] = *(const s16x8*)&Bs[(wc * 64 + nj * 16 + lo4) * 64 + kc * 32 + hi2 * 8];
#pragma unroll
      for (int mi = 0; mi < 4; ++mi)
#pragma unroll
        for (int nj = 0; nj < 4; ++nj)
          acc[mi][nj] = __builtin_amdgcn_mfma_f32_16x16x32_bf16(af[mi], bfr[nj], acc[mi][nj], 0, 0, 0);
    }
  }
#pragma unroll
  for (int mi = 0; mi < 4; ++mi)
#pragma unroll
    for (int nj = 0; nj < 4; ++nj)
#pragma unroll
      for (int r = 0; r < 4; ++r) {
        const int row = row0 + wr * 64 + mi * 16 + hi2 * 4 + r;
        const int col = col0 + wc * 64 + nj * 16 + lo4;
        C[(size_t)row * N + col] = f2bf(silu_(acc[mi][nj][r]));
      }
}

// ---------------- GEMM2: out = A2 @ WoT^T + b_out + hidden  M=4096 N=1024 K=3072, f32 out
__global__ __launch_bounds__(256) void hstu_gemm_out(const ushort_t* __restrict__ A,
                                                     const ushort_t* __restrict__ Bt,
                                                     const float* __restrict__ bout,
                                                     const float* __restrict__ hidden,
                                                     float* __restrict__ C) {
  constexpr int K = H3, N = Hh;
  __shared__ ushort_t As[128 * 64];
  __shared__ ushort_t Bs[64 * 64];
  const int tid = threadIdx.x, lane = tid & 63, wid = tid >> 6;
  const int lo4 = lane & 15, hi2 = lane >> 4;
  const int wr = wid >> 1, wc = wid & 1;
  const int row0 = blockIdx.y * 128, col0 = blockIdx.x * 64;
  const int srow = lane >> 3, scol = (lane & 7) * 8;
  f32x4v acc[4][2];
#pragma unroll
  for (int i = 0; i < 4; ++i)
#pragma unroll
    for (int j = 0; j < 2; ++j) acc[i][j] = {0.f, 0.f, 0.f, 0.f};

  for (int k0 = 0; k0 < K; k0 += 64) {
    __syncthreads();
#pragma unroll
    for (int i = 0; i < 4; ++i) {
      const int rb = wid * 32 + i * 8;
      g2l16(&A[(size_t)(row0 + rb + srow) * K + k0 + scol], &As[rb * 64]);
    }
#pragma unroll
    for (int i = 0; i < 2; ++i) {
      const int rb = wid * 16 + i * 8;
      g2l16(&Bt[(size_t)(col0 + rb + srow) * K + k0 + scol], &Bs[rb * 64]);
    }
    __syncthreads();
#pragma unroll
    for (int kc = 0; kc < 2; ++kc) {
      s16x8 af[4], bfr[2];
#pragma unroll
      for (int mi = 0; mi < 4; ++mi)
        af[mi] = *(const s16x8*)&As[(wr * 64 + mi * 16 + lo4) * 64 + kc * 32 + hi2 * 8];
#pragma unroll
      for (int nj = 0; nj < 2; ++nj)
        bfr[nj] = *(const s16x8*)&Bs[(wc * 32 + nj * 16 + lo4) * 64 + kc * 32 + hi2 * 8];
#pragma unroll
      for (int mi = 0; mi < 4; ++mi)
#pragma unroll
        for (int nj = 0; nj < 2; ++nj)
          acc[mi][nj] = __builtin_amdgcn_mfma_f32_16x16x32_bf16(af[mi], bfr[nj], acc[mi][nj], 0, 0, 0);
    }
  }
#pragma unroll
  for (int mi = 0; mi < 4; ++mi)
#pragma unroll
    for (int nj = 0; nj < 2; ++nj)
#pragma unroll
      for (int r = 0; r < 4; ++r) {
        const int row = row0 + wr * 64 + mi * 16 + hi2 * 4 + r;
        const int col = col0 + wc * 32 + nj * 16 + lo4;
        C[(size_t)row * N + col] = acc[mi][nj][r] + bout[col] + hidden[(size_t)row * N + col];
      }
}

// ---------------- fused attention, bf16 MFMA. Block: (b,h,64 q-rows), 8 waves, KVBLK=32.
// Writes a2 = attn_out * gated directly. a2 layout: [b][n][h*384 + {0:rope|128:ts|256:plain} + d]
__global__ __launch_bounds__(512, 4) void hstu_attn(const ushort_t* __restrict__ fused,
                                                    const ushort_t* __restrict__ qr,
                                                    const ushort_t* __restrict__ kr,
                                                    const ushort_t* __restrict__ vt,
                                                    const int* __restrict__ mask32,
                                                    const unsigned char* __restrict__ mask8,
                                                    const int* __restrict__ mflag,
                                                    const float* __restrict__ bias,
                                                    ushort_t* __restrict__ a2) {
  __shared__ __align__(16) ushort_t Ks[32][136];
  __shared__ __align__(16) ushort_t KRs[32][136];
  __shared__ __align__(16) ushort_t Vt[128][40];   // Vt[dd][m]
  __shared__ __align__(16) ushort_t Pl[3][64][40]; // 0=plain 1=rope 2=ts
  __shared__ __align__(16) ushort_t Mt[64][40];    // mask as bf16 0/1

  const int tid = threadIdx.x;
  const int lane = tid & 63;
  const int wid = tid >> 6;  // 0..7
  const int lo4 = lane & 15;
  const int hi2 = lane >> 4;
  const int n0 = blockIdx.x * 64;
  const int h = blockIdx.y;
  const int b = blockIdx.z;
  const float inv_s = 1.0f / 2048.0f;
  const int m_u8 = *mflag;

  // ---- hoist Q fragments: wave = (type t_w, row-quarter rq). Two staging passes via Ks/KRs.
  const int t_w = wid >> 2;  // 0=plain 1=rope
  const int rq = wid & 3;    // q-row quarter (16 rows)
  s16x8 qf[4];
  {
    const int row = tid >> 4;          // 0..31
    const int colg = (tid & 15) * 8;   // 0..120
#pragma unroll
    for (int half = 0; half < 2; ++half) {
      const size_t gr = (size_t)(b * Sq + n0 + half * 32 + row);
      *(s16x8*)&Ks[row][colg] = *(const s16x8*)&fused[gr * H6 + 4 * Hh + h * HD + colg];
      *(s16x8*)&KRs[row][colg] = *(const s16x8*)&qr[gr * Hh + h * HD + colg];
      __syncthreads();
      if ((rq >> 1) == half) {
        const int lrow = (rq & 1) * 16 + lo4;
        const ushort_t(*Qsrc)[136] = t_w ? KRs : Ks;
#pragma unroll
        for (int c = 0; c < 4; ++c)
          qf[c] = *(const s16x8*)&Qsrc[lrow][c * 32 + hi2 * 8];
      }
      __syncthreads();
    }
  }

  const f32x4v zero4 = {0.f, 0.f, 0.f, 0.f};
  f32x4v accO[3][2][2];  // [type][row-tile][col-tile]
#pragma unroll
  for (int t = 0; t < 3; ++t)
#pragma unroll
    for (int rt = 0; rt < 2; ++rt)
#pragma unroll
      for (int ct = 0; ct < 2; ++ct) accO[t][rt][ct] = zero4;

  const int rh2 = wid >> 2;  // PV row-half
  const int cq = wid & 3;    // PV dd-quarter

  for (int m0 = 0; m0 < Sq; m0 += 32) {
    // ---- stage: K, KR (copies), Vt (copy), ts scores + mask
    {
      const int row = tid >> 4;
      const int colg = (tid & 15) * 8;
      const size_t gr = (size_t)(b * Sq + m0 + row);
      *(s16x8*)&Ks[row][colg] = *(const s16x8*)&fused[gr * H6 + 5 * Hh + h * HD + colg];
      *(s16x8*)&KRs[row][colg] = *(const s16x8*)&kr[gr * Hh + h * HD + colg];
    }
    {
      const int dd = tid >> 2;
      const int mg = (tid & 3) * 8;
      *(s16x8*)&Vt[dd][mg] =
          *(const s16x8*)&vt[(size_t)((b * NH + h) * HD + dd) * Sq + m0 + mg];
    }
    {
      const int row = tid >> 3;        // 0..63
      const int mg = (tid & 7) * 4;    // 0..28
      const size_t ibase = (size_t)(b * Sq + n0 + row) * Sq + m0 + mg;
      int mk[4];
      if (m_u8) {
        uchar4 mu = *(const uchar4*)&mask8[ibase];
        mk[0] = mu.x; mk[1] = mu.y; mk[2] = mu.z; mk[3] = mu.w;
      } else {
        int4 mi = *(const int4*)&mask32[ibase];
        mk[0] = mi.x; mk[1] = mi.y; mk[2] = mi.z; mk[3] = mi.w;
      }
      float4 bv = *(const float4*)&bias[ibase];
      float bb[4] = {bv.x, bv.y, bv.z, bv.w};
      ushort4 tsb, mtb;
      ushort_t* tp = (ushort_t*)&tsb;
      ushort_t* mp_ = (ushort_t*)&mtb;
#pragma unroll
      for (int i = 0; i < 4; ++i) {
        tp[i] = f2bf(mk[i] ? bb[i] : 0.0f);
        mp_[i] = mk[i] ? 0x3f80u : 0u;  // bf16 1.0 / 0.0
      }
      *(ushort4*)&Pl[2][row][mg] = tsb;
      *(ushort4*)&Mt[row][mg] = mtb;
    }
    __syncthreads();
    // ---- scores: wave (t_w, rq) -> S[16 x 32] of its type
    {
      const ushort_t(*Kmat)[136] = t_w ? KRs : Ks;
#pragma unroll
      for (int mt2 = 0; mt2 < 2; ++mt2) {
        f32x4v a = zero4;
#pragma unroll
        for (int c = 0; c < 4; ++c) {
          s16x8 kf = *(const s16x8*)&Kmat[mt2 * 16 + lo4][c * 32 + hi2 * 8];
          a = __builtin_amdgcn_mfma_f32_16x16x32_bf16(qf[c], kf, a, 0, 0, 0);
        }
#pragma unroll
        for (int r = 0; r < 4; ++r) {
          const int n = rq * 16 + hi2 * 4 + r;
          const int m = mt2 * 16 + lo4;
          Pl[t_w][n][m] = f2bf(fmaxf(a[r], 0.f) * inv_s * bf2f(Mt[n][m]));
        }
      }
    }
    __syncthreads();
    // ---- PV: wave (rh2, cq): O[32 rows][32 dd] x 3 types
    {
      s16x8 af[3][2];
#pragma unroll
      for (int t = 0; t < 3; ++t)
#pragma unroll
        for (int rt = 0; rt < 2; ++rt)
          af[t][rt] = *(const s16x8*)&Pl[t][rh2 * 32 + rt * 16 + lo4][hi2 * 8];
      s16x8 bfv[2];
#pragma unroll
      for (int ct = 0; ct < 2; ++ct)
        bfv[ct] = *(const s16x8*)&Vt[cq * 32 + ct * 16 + lo4][hi2 * 8];
#pragma unroll
      for (int t = 0; t < 3; ++t)
#pragma unroll
        for (int rt = 0; rt < 2; ++rt)
#pragma unroll
          for (int ct = 0; ct < 2; ++ct)
            accO[t][rt][ct] =
                __builtin_amdgcn_mfma_f32_16x16x32_bf16(af[t][rt], bfv[ct], accO[t][rt][ct], 0, 0, 0);
    }
    __syncthreads();
  }

  // ---- epilogue: a2 = acc * gated (gated = fused[:, :3H], same 3H coordinate)
  const int toff[3] = {256, 0, 128};
#pragma unroll
  for (int t = 0; t < 3; ++t)
#pragma unroll
    for (int rt = 0; rt < 2; ++rt)
#pragma unroll
      for (int ct = 0; ct < 2; ++ct)
#pragma unroll
        for (int r = 0; r < 4; ++r) {
          const int n = n0 + rh2 * 32 + rt * 16 + hi2 * 4 + r;
          const int dd = cq * 32 + ct * 16 + lo4;
          const int col3 = h * 384 + toff[t] + dd;
          const float g = bf2f(fused[(size_t)(b * Sq + n) * H6 + col3]);
          a2[(size_t)(b * Sq + n) * H3 + col3] = f2bf(accO[t][rt][ct][r] * g);
        }
}

// ---------------- RMS norm in-place (4096 rows x 1024), f32
__global__ __launch_bounds__(256) void hstu_rms(float* __restrict__ y,
                                                const float* __restrict__ w) {
  __shared__ float red[4];
  const int row = blockIdx.x;
  const int tid = threadIdx.x;
  float4 v = *(float4*)&y[(size_t)row * Hh + tid * 4];
  float ss = v.x * v.x + v.y * v.y + v.z * v.z + v.w * v.w;
#pragma unroll
  for (int o = 32; o > 0; o >>= 1) ss += __shfl_down(ss, o);
  if ((tid & 63) == 0) red[tid >> 6] = ss;
  __syncthreads();
  const float tot = red[0] + red[1] + red[2] + red[3];
  const float r = 1.0f / sqrtf(tot / (float)Hh + 1e-6f);
  float4 wv = *(const float4*)&w[tid * 4];
  v.x *= r * wv.x;
  v.y *= r * wv.y;
  v.z *= r * wv.z;
  v.w *= r * wv.w;
  *(float4*)&y[(size_t)row * Hh + tid * 4] = v;
}

extern "C" void kernel_launch(void* const* d_in, const int* in_sizes, int n_in,
                              void* d_out, int out_size, void* d_ws, size_t ws_size,
                              hipStream_t stream) {
  const float* hidden = (const float*)d_in[0];
  const void* mask = d_in[1];
  const float* bias = (const float*)d_in[2];
  const float* Wqkvu = (const float*)d_in[3];
  const float* Wout = (const float*)d_in[4];
  const float* bout = (const float*)d_in[5];
  const float* rmsw = (const float*)d_in[6];
  float* out = (float*)d_out;
  float* ws = (float*)d_ws;

  ushort_t* fused = (ushort_t*)(ws + FUSED_OFF);
  ushort_t* a2 = (ushort_t*)(ws + A2_OFF);
  ushort_t* hb = (ushort_t*)(ws + HB_OFF);
  ushort_t* wqt = (ushort_t*)(ws + WQT_OFF);
  ushort_t* wot = (ushort_t*)(ws + WOT_OFF);
  ushort_t* qrb = (ushort_t*)(ws + QR_OFF);
  ushort_t* krb = (ushort_t*)(ws + KR_OFF);
  ushort_t* vtb = (ushort_t*)(ws + VT_OFF);
  float* tab = ws + TAB_OFF;
  int* mflag = (int*)(ws + FLAG_OFF);

  hstu_mask_detect<<<1, 256, 0, stream>>>((const unsigned int*)mask, mflag);
  hstu_tab<<<512, 256, 0, stream>>>(tab);
  hstu_cvt<<<4096, 256, 0, stream>>>(hidden, hb, (Bz * Sq * Hh) / 4);
  hstu_cvt_t<<<dim3(H6 / 32, Hh / 32), 256, 0, stream>>>(Wqkvu, wqt, Hh, H6);
  hstu_cvt_t<<<dim3(Hh / 32, H3 / 32), 256, 0, stream>>>(Wout, wot, H3, Hh);
  hstu_gemm_silu<<<dim3(H6 / 128, (Bz * Sq) / 128), 256, 0, stream>>>(hb, wqt, fused);
  hstu_rope<<<(Bz * Sq * Hh / 8) / 256, 256, 0, stream>>>(fused, (const float2*)tab, qrb, krb);
  hstu_vt<<<dim3(Sq / 32, HD / 32, Bz * NH), 256, 0, stream>>>(fused, vtb);
  hstu_attn<<<dim3(Sq / 64, NH, Bz), 512, 0, stream>>>(
      fused, qrb, krb, vtb, (const int*)mask, (const unsigned char*)mask, mflag, bias, a2);
  hstu_gemm_out<<<dim3(Hh / 64, (Bz * Sq) / 128), 256, 0, stream>>>(a2, wot, bout, hidden, out);
  hstu_rms<<<Bz * Sq, 256, 0, stream>>>(out, rmsw);
}

// Round 6
// 367.239 us; speedup vs baseline: 8.7810x; 1.0588x over previous
//
#include <hip/hip_runtime.h>
#include <math.h>

// Problem constants (B=2, S=2048, H=1024, NH=8, HD=128)
static constexpr int Bz = 2;
static constexpr int Sq = 2048;
static constexpr int Hh = 1024;
static constexpr int NH = 8;
static constexpr int HD = 128;
static constexpr int H3 = 3072;
static constexpr int H6 = 6144;

typedef unsigned short ushort_t;
typedef float f32x4v __attribute__((ext_vector_type(4)));
typedef short s16x8 __attribute__((ext_vector_type(8)));

// Workspace layout in float units (×4 bytes). Peak requirement ~146 MB (<=152 MB known-good).
static constexpr size_t FUSED_OFF = 0;          // bf16 [4096][6144] = 12,582,912 f
static constexpr size_t A2_OFF    = 12582912;   // bf16 [4096][3072] =  6,291,456 f
static constexpr size_t HB_OFF    = 18874368;   // bf16 [4096][1024] =  2,097,152 f (dead after gemm_silu)
static constexpr size_t MTB_OFF   = 18874368;   // bf16 [2][2048][2048] = 4,194,304 f (OVERLAYS hb+wqt)
static constexpr size_t WQT_OFF   = 20971520;   // bf16 [6144][1024] =  3,145,728 f (dead after gemm_silu)
static constexpr size_t WOT_OFF   = 24117248;   // bf16 [1024][3072] =  1,572,864 f
static constexpr size_t QR_OFF    = 25690112;   // bf16 [4096][1024] =  2,097,152 f
static constexpr size_t KR_OFF    = 27787264;   // bf16 [4096][1024] =  2,097,152 f
static constexpr size_t VT_OFF    = 29884416;   // bf16 [16][128][2048] = 2,097,152 f
static constexpr size_t TAB_OFF   = 31981568;   // f32 S*64 float2 = 262,144 f
static constexpr size_t FLAG_OFF  = 32243712;   // 1 int (+pad)
static constexpr size_t TSB_OFF   = 32243716;   // bf16 [2][2048][2048] = 4,194,304 f -> ends 36,438,020 f

__device__ __forceinline__ float silu_(float x) { return x / (1.0f + expf(-x)); }
__device__ __forceinline__ ushort_t f2bf(float x) {
  unsigned int u = __float_as_uint(x);
  u += 0x7fffu + ((u >> 16) & 1u);
  return (ushort_t)(u >> 16);
}
__device__ __forceinline__ float bf2f(ushort_t u) {
  return __uint_as_float(((unsigned int)u) << 16);
}
// async global->LDS 16B: per-lane global src, wave-uniform LDS base (+lane*16B by HW)
__device__ __forceinline__ void g2l16(const ushort_t* g, ushort_t* l) {
  __builtin_amdgcn_global_load_lds(
      (const __attribute__((address_space(1))) unsigned int*)g,
      (__attribute__((address_space(3))) unsigned int*)l, 16, 0, 0);
}

// ---------------- mask dtype detect: any 32-bit word > 1 => byte-packed bools
__global__ __launch_bounds__(256) void hstu_mask_detect(const unsigned int* __restrict__ m,
                                                        int* __restrict__ flag) {
  __shared__ int s_any;
  if (threadIdx.x == 0) s_any = 0;
  __syncthreads();
  int any = 0;
  for (int i = threadIdx.x; i < 65536; i += 256)
    if (m[i] > 1u) any = 1;
  if (any) s_any = 1;
  __syncthreads();
  if (threadIdx.x == 0) *flag = s_any;
}

// ---------------- rope table: tab[s*64+i] = {cos,sin}(s * 10000^(-i/64))
__global__ __launch_bounds__(256) void hstu_tab(float* __restrict__ tab) {
  int t = blockIdx.x * 256 + threadIdx.x;
  int i = t & 63;
  int s = t >> 6;
  float inv = powf(10000.0f, -(float)i / 64.0f);
  float sn, cs;
  sincosf((float)s * inv, &sn, &cs);
  tab[2 * t + 0] = cs;
  tab[2 * t + 1] = sn;
}

// ---------------- mask/bias precompute: tsb = bf16(mask?bias:0), mtb = bf16(mask?1:0)
__global__ __launch_bounds__(256) void hstu_msk(const int* __restrict__ mask32,
                                                const unsigned char* __restrict__ mask8,
                                                const int* __restrict__ mflag,
                                                const float* __restrict__ bias,
                                                ushort_t* __restrict__ tsb,
                                                ushort_t* __restrict__ mtb) {
  const size_t base = ((size_t)blockIdx.x * 256 + threadIdx.x) * 8;  // over B*S*S
  const int m_u8 = *mflag;
  int mk[8];
  if (m_u8) {
    uchar4 a = *(const uchar4*)&mask8[base];
    uchar4 b = *(const uchar4*)&mask8[base + 4];
    mk[0] = a.x; mk[1] = a.y; mk[2] = a.z; mk[3] = a.w;
    mk[4] = b.x; mk[5] = b.y; mk[6] = b.z; mk[7] = b.w;
  } else {
    int4 a = *(const int4*)&mask32[base];
    int4 b = *(const int4*)&mask32[base + 4];
    mk[0] = a.x; mk[1] = a.y; mk[2] = a.z; mk[3] = a.w;
    mk[4] = b.x; mk[5] = b.y; mk[6] = b.z; mk[7] = b.w;
  }
  float4 b0 = *(const float4*)&bias[base];
  float4 b1 = *(const float4*)&bias[base + 4];
  float bb[8] = {b0.x, b0.y, b0.z, b0.w, b1.x, b1.y, b1.z, b1.w};
  ushort_t ts[8], mt[8];
#pragma unroll
  for (int i = 0; i < 8; ++i) {
    ts[i] = f2bf(mk[i] ? bb[i] : 0.0f);
    mt[i] = mk[i] ? 0x3f80u : 0u;
  }
  *(s16x8*)&tsb[base] = *(s16x8*)ts;
  *(s16x8*)&mtb[base] = *(s16x8*)mt;
}

// ---------------- f32 -> bf16 row-major copy (hidden)
__global__ __launch_bounds__(256) void hstu_cvt(const float* __restrict__ in,
                                                ushort_t* __restrict__ out, int n4) {
  int i = blockIdx.x * 256 + threadIdx.x;
  if (i >= n4) return;
  float4 v = *(const float4*)&in[(size_t)i * 4];
  ushort4 o;
  o.x = f2bf(v.x); o.y = f2bf(v.y); o.z = f2bf(v.z); o.w = f2bf(v.w);
  *(ushort4*)&out[(size_t)i * 4] = o;
}

// ---------------- f32 [K][N] -> bf16 [N][K] transpose-convert (weights)
__global__ __launch_bounds__(256) void hstu_cvt_t(const float* __restrict__ in,
                                                  ushort_t* __restrict__ out, int K, int N) {
  __shared__ float t[32][33];
  const int n0 = blockIdx.x * 32, k0 = blockIdx.y * 32;
  const int c = threadIdx.x & 31, rr = threadIdx.x >> 5;
#pragma unroll
  for (int p = 0; p < 4; ++p)
    t[rr + p * 8][c] = in[(size_t)(k0 + rr + p * 8) * N + n0 + c];
  __syncthreads();
#pragma unroll
  for (int p = 0; p < 4; ++p)
    out[(size_t)(n0 + rr + p * 8) * K + k0 + c] = f2bf(t[c][rr + p * 8]);
}

// ---------------- rope precompute: qr/kr[b][s][h*128+d] = rope(fused q/k), bf16
__global__ __launch_bounds__(256) void hstu_rope(const ushort_t* __restrict__ fused,
                                                 const float2* __restrict__ tab,
                                                 ushort_t* __restrict__ qr,
                                                 ushort_t* __restrict__ kr) {
  const int idx = blockIdx.x * 256 + threadIdx.x;  // over 4096*1024/8
  const int row = idx >> 7;
  const int cg = (idx & 127) * 8;
  const int s = row & (Sq - 1);
  const float2* trow = &tab[(size_t)s * 64 + ((cg & 127) >> 1)];
  float2 t[4];
#pragma unroll
  for (int p = 0; p < 4; ++p) t[p] = trow[p];

  s16x8 q8 = *(const s16x8*)&fused[(size_t)row * H6 + 4 * Hh + cg];
  s16x8 k8 = *(const s16x8*)&fused[(size_t)row * H6 + 5 * Hh + cg];
  ushort_t qo[8], ko[8];
#pragma unroll
  for (int p = 0; p < 4; ++p) {
    float qx = bf2f((ushort_t)q8[2 * p]), qy = bf2f((ushort_t)q8[2 * p + 1]);
    float kx = bf2f((ushort_t)k8[2 * p]), ky = bf2f((ushort_t)k8[2 * p + 1]);
    qo[2 * p] = f2bf(qx * t[p].x - qy * t[p].y);
    qo[2 * p + 1] = f2bf(qy * t[p].x + qx * t[p].y);
    ko[2 * p] = f2bf(kx * t[p].x - ky * t[p].y);
    ko[2 * p + 1] = f2bf(ky * t[p].x + kx * t[p].y);
  }
  *(s16x8*)&qr[(size_t)row * Hh + cg] = *(s16x8*)qo;
  *(s16x8*)&kr[(size_t)row * Hh + cg] = *(s16x8*)ko;
}

// ---------------- V transpose precompute: vt[(b*8+h)*128+dd][m] = V[b][m][h*128+dd]
__global__ __launch_bounds__(256) void hstu_vt(const ushort_t* __restrict__ fused,
                                               ushort_t* __restrict__ vt) {
  __shared__ ushort_t t[32][36];
  const int m0 = blockIdx.x * 32, d0 = blockIdx.y * 32, bh = blockIdx.z;
  const int b = bh >> 3, h = bh & 7;
  const int r = threadIdx.x >> 3, cg = (threadIdx.x & 7) * 4;
  *(ushort4*)&t[r][cg] =
      *(const ushort4*)&fused[(size_t)(b * Sq + m0 + r) * H6 + 3 * Hh + h * HD + d0 + cg];
  __syncthreads();
  ushort4 o;
  o.x = t[cg + 0][r]; o.y = t[cg + 1][r]; o.z = t[cg + 2][r]; o.w = t[cg + 3][r];
  *(ushort4*)&vt[(size_t)(bh * HD + d0 + r) * Sq + m0 + cg] = o;
}

// ---------------- GEMM1: fused = silu(hidden_bf @ WqT^T)  M=4096 N=6144 K=1024, bf16 out
__global__ __launch_bounds__(256) void hstu_gemm_silu(const ushort_t* __restrict__ A,
                                                      const ushort_t* __restrict__ Bt,
                                                      ushort_t* __restrict__ C) {
  constexpr int K = 1024, N = H6;
  __shared__ ushort_t As[128 * 64];
  __shared__ ushort_t Bs[128 * 64];
  const int tid = threadIdx.x, lane = tid & 63, wid = tid >> 6;
  const int lo4 = lane & 15, hi2 = lane >> 4;
  const int wr = wid >> 1, wc = wid & 1;
  const int row0 = blockIdx.y * 128, col0 = blockIdx.x * 128;
  const int srow = lane >> 3, scol = (lane & 7) * 8;
  f32x4v acc[4][4];
#pragma unroll
  for (int i = 0; i < 4; ++i)
#pragma unroll
    for (int j = 0; j < 4; ++j) acc[i][j] = {0.f, 0.f, 0.f, 0.f};

  for (int k0 = 0; k0 < K; k0 += 64) {
    __syncthreads();
#pragma unroll
    for (int i = 0; i < 4; ++i) {
      const int rb = wid * 32 + i * 8;
      g2l16(&A[(size_t)(row0 + rb + srow) * K + k0 + scol], &As[rb * 64]);
      g2l16(&Bt[(size_t)(col0 + rb + srow) * K + k0 + scol], &Bs[rb * 64]);
    }
    __syncthreads();
#pragma unroll
    for (int kc = 0; kc < 2; ++kc) {
      s16x8 af[4], bfr[4];
#pragma unroll
      for (int mi = 0; mi < 4; ++mi)
        af[mi] = *(const s16x8*)&As[(wr * 64 + mi * 16 + lo4) * 64 + kc * 32 + hi2 * 8];
#pragma unroll
      for (int nj = 0; nj < 4; ++nj)
        bfr[nj] = *(const s16x8*)&Bs[(wc * 64 + nj * 16 + lo4) * 64 + kc * 32 + hi2 * 8];
#pragma unroll
      for (int mi = 0; mi < 4; ++mi)
#pragma unroll
        for (int nj = 0; nj < 4; ++nj)
          acc[mi][nj] = __builtin_amdgcn_mfma_f32_16x16x32_bf16(af[mi], bfr[nj], acc[mi][nj], 0, 0, 0);
    }
  }
#pragma unroll
  for (int mi = 0; mi < 4; ++mi)
#pragma unroll
    for (int nj = 0; nj < 4; ++nj)
#pragma unroll
      for (int r = 0; r < 4; ++r) {
        const int row = row0 + wr * 64 + mi * 16 + hi2 * 4 + r;
        const int col = col0 + wc * 64 + nj * 16 + lo4;
        C[(size_t)row * N + col] = f2bf(silu_(acc[mi][nj][r]));
      }
}

// ---------------- GEMM2: out = A2 @ WoT^T + b_out + hidden  M=4096 N=1024 K=3072, f32 out
__global__ __launch_bounds__(256) void hstu_gemm_out(const ushort_t* __restrict__ A,
                                                     const ushort_t* __restrict__ Bt,
                                                     const float* __restrict__ bout,
                                                     const float* __restrict__ hidden,
                                                     float* __restrict__ C) {
  constexpr int K = H3, N = Hh;
  __shared__ ushort_t As[128 * 64];
  __shared__ ushort_t Bs[64 * 64];
  const int tid = threadIdx.x, lane = tid & 63, wid = tid >> 6;
  const int lo4 = lane & 15, hi2 = lane >> 4;
  const int wr = wid >> 1, wc = wid & 1;
  const int row0 = blockIdx.y * 128, col0 = blockIdx.x * 64;
  const int srow = lane >> 3, scol = (lane & 7) * 8;
  f32x4v acc[4][2];
#pragma unroll
  for (int i = 0; i < 4; ++i)
#pragma unroll
    for (int j = 0; j < 2; ++j) acc[i][j] = {0.f, 0.f, 0.f, 0.f};

  for (int k0 = 0; k0 < K; k0 += 64) {
    __syncthreads();
#pragma unroll
    for (int i = 0; i < 4; ++i) {
      const int rb = wid * 32 + i * 8;
      g2l16(&A[(size_t)(row0 + rb + srow) * K + k0 + scol], &As[rb * 64]);
    }
#pragma unroll
    for (int i = 0; i < 2; ++i) {
      const int rb = wid * 16 + i * 8;
      g2l16(&Bt[(size_t)(col0 + rb + srow) * K + k0 + scol], &Bs[rb * 64]);
    }
    __syncthreads();
#pragma unroll
    for (int kc = 0; kc < 2; ++kc) {
      s16x8 af[4], bfr[2];
#pragma unroll
      for (int mi = 0; mi < 4; ++mi)
        af[mi] = *(const s16x8*)&As[(wr * 64 + mi * 16 + lo4) * 64 + kc * 32 + hi2 * 8];
#pragma unroll
      for (int nj = 0; nj < 2; ++nj)
        bfr[nj] = *(const s16x8*)&Bs[(wc * 32 + nj * 16 + lo4) * 64 + kc * 32 + hi2 * 8];
#pragma unroll
      for (int mi = 0; mi < 4; ++mi)
#pragma unroll
        for (int nj = 0; nj < 2; ++nj)
          acc[mi][nj] = __builtin_amdgcn_mfma_f32_16x16x32_bf16(af[mi], bfr[nj], acc[mi][nj], 0, 0, 0);
    }
  }
#pragma unroll
  for (int mi = 0; mi < 4; ++mi)
#pragma unroll
    for (int nj = 0; nj < 2; ++nj)
#pragma unroll
      for (int r = 0; r < 4; ++r) {
        const int row = row0 + wr * 64 + mi * 16 + hi2 * 4 + r;
        const int col = col0 + wc * 32 + nj * 16 + lo4;
        C[(size_t)row * N + col] = acc[mi][nj][r] + bout[col] + hidden[(size_t)row * N + col];
      }
}

// ---------------- fused attention, bf16 MFMA. Block: (h, nblock, b), 8 waves, KVBLK=32.
// T14 split staging: issue loads(t+1) before compute(t), ds_write after PV barrier.
// Writes a2 = attn_out * gated. a2 layout: [b][n][h*384 + {0:rope|128:ts|256:plain} + d]
__global__ __launch_bounds__(512, 4) void hstu_attn(const ushort_t* __restrict__ fused,
                                                    const ushort_t* __restrict__ qr,
                                                    const ushort_t* __restrict__ kr,
                                                    const ushort_t* __restrict__ vt,
                                                    const ushort_t* __restrict__ tsb,
                                                    const ushort_t* __restrict__ mtb,
                                                    ushort_t* __restrict__ a2) {
  __shared__ __align__(16) ushort_t Ks[32][136];
  __shared__ __align__(16) ushort_t KRs[32][136];
  __shared__ __align__(16) ushort_t Vt[128][40];   // Vt[dd][m]
  __shared__ __align__(16) ushort_t Pl[3][64][40]; // 0=plain 1=rope 2=ts
  __shared__ __align__(16) ushort_t Mt[64][40];    // mask as bf16 0/1

  const int tid = threadIdx.x;
  const int lane = tid & 63;
  const int wid = tid >> 6;  // 0..7
  const int lo4 = lane & 15;
  const int hi2 = lane >> 4;
  const int h = blockIdx.x;        // x = head -> linear%8 = h -> XCD pinning
  const int n0 = blockIdx.y * 64;
  const int b = blockIdx.z;
  const float inv_s = 1.0f / 2048.0f;

  // staging index constants
  const int krow = tid >> 4, kcol = (tid & 15) * 8;       // K/KR: 32 x 128
  const int vdd = tid >> 2, vmg = (tid & 3) * 8;          // Vt: 128 x 32
  const int trow = (tid & 255) >> 2, tmg = (tid & 3) * 8; // ts/mask: 64 x 32 (256 thr each)
  const ushort_t* TM = (wid < 4) ? tsb : mtb;             // waves 0-3: tsb, 4-7: mtb
  const size_t kbase = (size_t)b * Sq * H6 + 5 * Hh + h * HD + kcol;
  const size_t krbase = (size_t)b * Sq * Hh + h * HD + kcol;
  const size_t vbase = (size_t)((b * NH + h) * HD + vdd) * Sq + vmg;
  const size_t tbase = (size_t)(b * Sq + n0 + trow) * Sq + tmg;

  // ---- hoist Q fragments: wave = (type t_w, row-quarter rq)
  const int t_w = wid >> 2;  // 0=plain 1=rope
  const int rq = wid & 3;
  s16x8 qf[4];
  {
    const int row = tid >> 4;
    const int colg = (tid & 15) * 8;
#pragma unroll
    for (int half = 0; half < 2; ++half) {
      const size_t gr = (size_t)(b * Sq + n0 + half * 32 + row);
      *(s16x8*)&Ks[row][colg] = *(const s16x8*)&fused[gr * H6 + 4 * Hh + h * HD + colg];
      *(s16x8*)&KRs[row][colg] = *(const s16x8*)&qr[gr * Hh + h * HD + colg];
      __syncthreads();
      if ((rq >> 1) == half) {
        const int lrow = (rq & 1) * 16 + lo4;
        const ushort_t(*Qsrc)[136] = t_w ? KRs : Ks;
#pragma unroll
        for (int c = 0; c < 4; ++c)
          qf[c] = *(const s16x8*)&Qsrc[lrow][c * 32 + hi2 * 8];
      }
      __syncthreads();
    }
  }

  const f32x4v zero4 = {0.f, 0.f, 0.f, 0.f};
  f32x4v accO[3][2][2];
#pragma unroll
  for (int t = 0; t < 3; ++t)
#pragma unroll
    for (int rt = 0; rt < 2; ++rt)
#pragma unroll
      for (int ct = 0; ct < 2; ++ct) accO[t][rt][ct] = zero4;

  const int rh2 = wid >> 2;  // PV row-half
  const int cq = wid & 3;    // PV dd-quarter

  // prefetch registers
  s16x8 kreg, krreg, vreg, tmreg;
#define LOADT(T)                                                            \
  {                                                                         \
    const size_t moff = (size_t)(T) * 32;                                   \
    kreg = *(const s16x8*)&fused[kbase + (moff + krow) * H6];               \
    krreg = *(const s16x8*)&kr[krbase + (moff + krow) * Hh];                \
    vreg = *(const s16x8*)&vt[vbase + moff];                                \
    tmreg = *(const s16x8*)&TM[tbase + moff];                               \
  }
#define WRITET()                                                            \
  {                                                                         \
    *(s16x8*)&Ks[krow][kcol] = kreg;                                        \
    *(s16x8*)&KRs[krow][kcol] = krreg;                                      \
    *(s16x8*)&Vt[vdd][vmg] = vreg;                                          \
    if (wid < 4) *(s16x8*)&Pl[2][trow][tmg] = tmreg;                        \
    else *(s16x8*)&Mt[trow][tmg] = tmreg;                                   \
  }

  LOADT(0);
  WRITET();
  __syncthreads();

  for (int t = 0; t < Sq / 32; ++t) {
    if (t + 1 < Sq / 32) LOADT(t + 1);  // issue early (T14)
    // ---- scores: wave (t_w, rq) -> S[16 x 32] of its type
    {
      const ushort_t(*Kmat)[136] = t_w ? KRs : Ks;
#pragma unroll
      for (int mt2 = 0; mt2 < 2; ++mt2) {
        f32x4v a = zero4;
#pragma unroll
        for (int c = 0; c < 4; ++c) {
          s16x8 kf = *(const s16x8*)&Kmat[mt2 * 16 + lo4][c * 32 + hi2 * 8];
          a = __builtin_amdgcn_mfma_f32_16x16x32_bf16(qf[c], kf, a, 0, 0, 0);
        }
#pragma unroll
        for (int r = 0; r < 4; ++r) {
          const int n = rq * 16 + hi2 * 4 + r;
          const int m = mt2 * 16 + lo4;
          Pl[t_w][n][m] = f2bf(fmaxf(a[r], 0.f) * inv_s * bf2f(Mt[n][m]));
        }
      }
    }
    __syncthreads();
    // ---- PV: wave (rh2, cq): O[32 rows][32 dd] x 3 types
    {
      s16x8 af[3][2];
#pragma unroll
      for (int ty = 0; ty < 3; ++ty)
#pragma unroll
        for (int rt = 0; rt < 2; ++rt)
          af[ty][rt] = *(const s16x8*)&Pl[ty][rh2 * 32 + rt * 16 + lo4][hi2 * 8];
      s16x8 bfv[2];
#pragma unroll
      for (int ct = 0; ct < 2; ++ct)
        bfv[ct] = *(const s16x8*)&Vt[cq * 32 + ct * 16 + lo4][hi2 * 8];
#pragma unroll
      for (int ty = 0; ty < 3; ++ty)
#pragma unroll
        for (int rt = 0; rt < 2; ++rt)
#pragma unroll
          for (int ct = 0; ct < 2; ++ct)
            accO[ty][rt][ct] =
                __builtin_amdgcn_mfma_f32_16x16x32_bf16(af[ty][rt], bfv[ct], accO[ty][rt][ct], 0, 0, 0);
    }
    __syncthreads();
    // ---- write prefetched tile t+1 into LDS (write late, T14)
    if (t + 1 < Sq / 32) WRITET();
    __syncthreads();
  }
#undef LOADT
#undef WRITET

  // ---- epilogue: a2 = acc * gated (gated = fused[:, :3H], same 3H coordinate)
  const int toff[3] = {256, 0, 128};
#pragma unroll
  for (int ty = 0; ty < 3; ++ty)
#pragma unroll
    for (int rt = 0; rt < 2; ++rt)
#pragma unroll
      for (int ct = 0; ct < 2; ++ct)
#pragma unroll
        for (int r = 0; r < 4; ++r) {
          const int n = n0 + rh2 * 32 + rt * 16 + hi2 * 4 + r;
          const int dd = cq * 32 + ct * 16 + lo4;
          const int col3 = h * 384 + toff[ty] + dd;
          const float g = bf2f(fused[(size_t)(b * Sq + n) * H6 + col3]);
          a2[(size_t)(b * Sq + n) * H3 + col3] = f2bf(accO[ty][rt][ct][r] * g);
        }
}

// ---------------- RMS norm in-place (4096 rows x 1024), f32
__global__ __launch_bounds__(256) void hstu_rms(float* __restrict__ y,
                                                const float* __restrict__ w) {
  __shared__ float red[4];
  const int row = blockIdx.x;
  const int tid = threadIdx.x;
  float4 v = *(float4*)&y[(size_t)row * Hh + tid * 4];
  float ss = v.x * v.x + v.y * v.y + v.z * v.z + v.w * v.w;
#pragma unroll
  for (int o = 32; o > 0; o >>= 1) ss += __shfl_down(ss, o);
  if ((tid & 63) == 0) red[tid >> 6] = ss;
  __syncthreads();
  const float tot = red[0] + red[1] + red[2] + red[3];
  const float r = 1.0f / sqrtf(tot / (float)Hh + 1e-6f);
  float4 wv = *(const float4*)&w[tid * 4];
  v.x *= r * wv.x;
  v.y *= r * wv.y;
  v.z *= r * wv.z;
  v.w *= r * wv.w;
  *(float4*)&y[(size_t)row * Hh + tid * 4] = v;
}

extern "C" void kernel_launch(void* const* d_in, const int* in_sizes, int n_in,
                              void* d_out, int out_size, void* d_ws, size_t ws_size,
                              hipStream_t stream) {
  const float* hidden = (const float*)d_in[0];
  const void* mask = d_in[1];
  const float* bias = (const float*)d_in[2];
  const float* Wqkvu = (const float*)d_in[3];
  const float* Wout = (const float*)d_in[4];
  const float* bout = (const float*)d_in[5];
  const float* rmsw = (const float*)d_in[6];
  float* out = (float*)d_out;
  float* ws = (float*)d_ws;

  ushort_t* fused = (ushort_t*)(ws + FUSED_OFF);
  ushort_t* a2 = (ushort_t*)(ws + A2_OFF);
  ushort_t* hb = (ushort_t*)(ws + HB_OFF);
  ushort_t* mtbp = (ushort_t*)(ws + MTB_OFF);  // overlays hb/wqt (dead after gemm_silu)
  ushort_t* wqt = (ushort_t*)(ws + WQT_OFF);
  ushort_t* wot = (ushort_t*)(ws + WOT_OFF);
  ushort_t* qrb = (ushort_t*)(ws + QR_OFF);
  ushort_t* krb = (ushort_t*)(ws + KR_OFF);
  ushort_t* vtb = (ushort_t*)(ws + VT_OFF);
  float* tab = ws + TAB_OFF;
  int* mflag = (int*)(ws + FLAG_OFF);
  ushort_t* tsbp = (ushort_t*)(ws + TSB_OFF);

  hstu_mask_detect<<<1, 256, 0, stream>>>((const unsigned int*)mask, mflag);
  hstu_tab<<<512, 256, 0, stream>>>(tab);
  hstu_cvt<<<4096, 256, 0, stream>>>(hidden, hb, (Bz * Sq * Hh) / 4);
  hstu_cvt_t<<<dim3(H6 / 32, Hh / 32), 256, 0, stream>>>(Wqkvu, wqt, Hh, H6);
  hstu_cvt_t<<<dim3(Hh / 32, H3 / 32), 256, 0, stream>>>(Wout, wot, H3, Hh);
  hstu_gemm_silu<<<dim3(H6 / 128, (Bz * Sq) / 128), 256, 0, stream>>>(hb, wqt, fused);
  // msk AFTER gemm_silu: mtb overlays hb/wqt
  hstu_msk<<<(Bz * Sq * Sq / 8) / 256, 256, 0, stream>>>(
      (const int*)mask, (const unsigned char*)mask, mflag, bias, tsbp, mtbp);
  hstu_rope<<<(Bz * Sq * Hh / 8) / 256, 256, 0, stream>>>(fused, (const float2*)tab, qrb, krb);
  hstu_vt<<<dim3(Sq / 32, HD / 32, Bz * NH), 256, 0, stream>>>(fused, vtb);
  hstu_attn<<<dim3(NH, Sq / 64, Bz), 512, 0, stream>>>(fused, qrb, krb, vtb, tsbp, mtbp, a2);
  hstu_gemm_out<<<dim3(Hh / 64, (Bz * Sq) / 128), 256, 0, stream>>>(a2, wot, bout, hidden, out);
  hstu_rms<<<Bz * Sq, 256, 0, stream>>>(out, rmsw);
}